// Round 1
// 625.906 us; speedup vs baseline: 1.0320x; 1.0320x over previous
//
#include <hip/hip_runtime.h>
#include <math.h>

// ---------------------------------------------------------------------------
// SpatialGNN: 3x GCN (residual) + 4-head GAT + MLP + log_softmax
// N=100000, E=1600000, IN=8, HID=64, HEADS=4, OUT=3
//
// R11 changes vs R10:
//  - gat_agg: attention weights computed ONCE per edge (4 expf/lane per
//    64-edge batch) and staged in per-wave LDS as float4 together with the
//    source index; inner loop is ds_read_b32 + ds_read_b128 + 16B gather +
//    32 FMA. Removes the 8x t-redundant exp/leaky/a_src4 work and the
//    per-slot valid cndmask (validity folded into w=0).
//  - gat_agg + gcn_layer64 edge loops: branch-free full-16 pairs plus an
//    8-granular guarded tail (was 16-granular) — Poisson(16) degrees waste
//    43% slots at 16-granularity, 22% at 8.
// ---------------------------------------------------------------------------

typedef _Float16 half8 __attribute__((ext_vector_type(8)));
typedef _Float16 half2v __attribute__((ext_vector_type(2)));

__device__ __forceinline__ float leaky02(float v) { return v > 0.f ? v : 0.2f * v; }

// ---- cross-lane reduction helpers (DPP/swizzle; minimize DS-pipe ops) -----

template <int CTRL>
__device__ __forceinline__ float dpp_add(float v) {
    int iv = __builtin_bit_cast(int, v);
    int r = __builtin_amdgcn_update_dpp(iv, iv, CTRL, 0xF, 0xF, false);
    return v + __builtin_bit_cast(float, r);
}
template <int OFF>
__device__ __forceinline__ float swz_add(float v) {
    int r = __builtin_amdgcn_ds_swizzle(__builtin_bit_cast(int, v), OFF);
    return v + __builtin_bit_cast(float, r);
}
__device__ __forceinline__ float red8(float v) {
    v = dpp_add<0xB1>(v);     // xor1
    v = dpp_add<0x4E>(v);     // xor2
    v = swz_add<0x101F>(v);   // xor4
    return v;
}
__device__ __forceinline__ float red64(float v) {
    v = dpp_add<0xB1>(v);
    v = dpp_add<0x4E>(v);
    v = swz_add<0x101F>(v);
    v = dpp_add<0x128>(v);    // xor8: row_ror:8
    v = swz_add<0x401F>(v);   // xor16
    v = v + __shfl_xor(v, 32);
    return v;
}
__device__ __forceinline__ float sel4(int g, float v0, float v1, float v2, float v3) {
    return g == 0 ? v0 : g == 1 ? v1 : g == 2 ? v2 : v3;
}

// ---- CSR build ------------------------------------------------------------

// XCD-range-filtered count: group blockIdx&7 counts only its dst range.
__global__ void count_kernel(const int* __restrict__ dst, int E, int range,
                             int* __restrict__ counts) {
    int grp = blockIdx.x & 7;
    int nlo = grp * range;
    int nhi = nlo + range;
    int nblk = gridDim.x >> 3;
    int c = blockIdx.x >> 3;
    int stride = nblk * blockDim.x;
    for (int e = c * blockDim.x + threadIdx.x; e < E; e += stride) {
        int d = dst[e];
        if (d >= nlo && d < nhi) atomicAdd(&counts[d], 1);
    }
}

__global__ void scan_pass1(const int* __restrict__ counts, int n, int* __restrict__ blockSums) {
    __shared__ int sh[256];
    int base = blockIdx.x * 2048;
    int tid = threadIdx.x;
    int s = 0;
#pragma unroll
    for (int j = 0; j < 8; ++j) {
        int idx = base + tid * 8 + j;
        if (idx < n) s += counts[idx];
    }
    sh[tid] = s;
    __syncthreads();
    for (int off = 128; off > 0; off >>= 1) {
        if (tid < off) sh[tid] += sh[tid + off];
        __syncthreads();
    }
    if (tid == 0) blockSums[blockIdx.x] = sh[0];
}

__global__ void scan_pass2(const int* __restrict__ blockSums, int nb, int* __restrict__ blockOffs) {
    if (threadIdx.x == 0 && blockIdx.x == 0) {
        int run = 0;
        for (int i = 0; i < nb; ++i) { blockOffs[i] = run; run += blockSums[i]; }
    }
}

__global__ void scan_pass3(const int* __restrict__ counts, int n,
                           const int* __restrict__ blockOffs,
                           const float* __restrict__ x,
                           int* __restrict__ row_ptr, int* __restrict__ cursor,
                           float* __restrict__ dinv, float* __restrict__ rdinv,
                           _Float16* __restrict__ xs) {
    __shared__ int sh[256];
    int base = blockIdx.x * 2048;
    int tid = threadIdx.x;
    int cnt[8];
    int local = 0;
#pragma unroll
    for (int j = 0; j < 8; ++j) {
        int idx = base + tid * 8 + j;
        cnt[j] = (idx < n) ? counts[idx] : 0;
        local += cnt[j];
    }
    sh[tid] = local;
    __syncthreads();
    for (int off = 1; off < 256; off <<= 1) {
        int v = (tid >= off) ? sh[tid - off] : 0;
        __syncthreads();
        sh[tid] += v;
        __syncthreads();
    }
    int run = blockOffs[blockIdx.x] + sh[tid] - local;
#pragma unroll
    for (int j = 0; j < 8; ++j) {
        int idx = base + tid * 8 + j;
        if (idx < n) {
            row_ptr[idx] = run;
            cursor[idx] = run;
            float dv = rsqrtf((float)(cnt[j] + 1));
            dinv[idx] = dv;
            rdinv[idx] = sqrtf((float)(cnt[j] + 1));
#pragma unroll
            for (int t = 0; t < 8; ++t) xs[idx * 8 + t] = (_Float16)(dv * x[idx * 8 + t]);
            run += cnt[j];
            if (idx == n - 1) row_ptr[n] = run;
        }
    }
}

// XCD-range-filtered scatter (R9, kept): col_src/cursor writes stay XCD-local.
__global__ void scatter_kernel(const int* __restrict__ src, const int* __restrict__ dst,
                               int E, int range,
                               int* __restrict__ cursor, int* __restrict__ col_src) {
    int grp = blockIdx.x & 7;
    int nlo = grp * range;
    int nhi = nlo + range;
    int nblk = gridDim.x >> 3;
    int c = blockIdx.x >> 3;
    int stride = nblk * blockDim.x;
    for (int e = c * blockDim.x + threadIdx.x; e < E; e += stride) {
        int d = dst[e];
        if (d >= nlo && d < nhi) {
            int pos = atomicAdd(&cursor[d], 1);
            col_src[pos] = src[e];
        }
    }
}

// ---- weight precompute: Ccomb/bcomb + attention-effective vectors ---------

__global__ void ccomb_kernel(const float* __restrict__ Wg, const float* __restrict__ bg,
                             const float* __restrict__ wc1, const float* __restrict__ bc1,
                             const float* __restrict__ att_src, const float* __restrict__ att_dst,
                             float* __restrict__ Ccomb, float* __restrict__ bcomb,
                             float* __restrict__ wse, float* __restrict__ wde) {
    int bid = blockIdx.x;   // 0..256
    int j = threadIdx.x;    // 64 threads
    if (bid < 256) {
        int h = bid >> 6, k = bid & 63;
        float s = 0.f;
        for (int c = 0; c < 64; ++c)
            s += Wg[k * 256 + h * 64 + c] * wc1[(h * 64 + c) * 64 + j];
        Ccomb[bid * 64 + j] = s;
    } else {
        float s = bc1[j];
        for (int i = 0; i < 256; ++i) s += bg[i] * wc1[i * 64 + j];
        bcomb[j] = s;
#pragma unroll
        for (int h = 0; h < 4; ++h) {
            float ss = 0.f, sd = 0.f;
            for (int c = 0; c < 64; ++c) {
                float w = Wg[j * 256 + h * 64 + c];
                ss += w * att_src[h * 64 + c];
                sd += w * att_dst[h * 64 + c];
            }
            wse[j * 4 + h] = ss;
            wde[j * 4 + h] = sd;
        }
    }
}

// ---- GCN layer 1: one edge per lane (16B half8 row) -----------------------

__global__ void gcn_layer1(const half8* __restrict__ xs8,
                           const float* __restrict__ W1, const float* __restrict__ b1,
                           const int* __restrict__ row_ptr, const int* __restrict__ col_src,
                           const float* __restrict__ dinv, int n,
                           _Float16* __restrict__ hs1) {
    int tid = threadIdx.x, lane = tid & 63, wid = tid >> 6;
    int node = blockIdx.x * 4 + wid;
    if (node >= n) return;
    int beg = row_ptr[node], end = row_ptr[node + 1];
    int deg = end - beg;
    float acc[8] = {0.f, 0.f, 0.f, 0.f, 0.f, 0.f, 0.f, 0.f};
    for (int base = 0; base < deg; base += 64) {
        int cs = col_src[min(beg + base + lane, end - 1)];
        half8 v = xs8[cs];
        if (base + lane < deg) {
#pragma unroll
            for (int c = 0; c < 8; ++c) acc[c] += (float)v[c];
        }
    }
#pragma unroll
    for (int c = 0; c < 8; ++c) acc[c] = red64(acc[c]);
    half8 sv = xs8[node];
    float di = dinv[node];
    float agg[8];
#pragma unroll
    for (int c = 0; c < 8; ++c) agg[c] = (acc[c] + (float)sv[c]) * di;
    float sum = b1[lane];
#pragma unroll
    for (int k = 0; k < 8; ++k) sum = fmaf(agg[k], W1[k * 64 + lane], sum);
    hs1[node * 64 + lane] = (_Float16)(di * fmaxf(sum, 0.f));
}

// ---- GCN layer 2/3: g=lane&7 edge slots, t=lane>>3 channel chunks ---------

template <bool LAST>
__global__ void gcn_layer64(const _Float16* __restrict__ hs_in,
                            const float* __restrict__ W, const float* __restrict__ b,
                            const int* __restrict__ row_ptr, const int* __restrict__ col_src,
                            const float* __restrict__ dinv, const float* __restrict__ rdinv,
                            const float* __restrict__ wse, const float* __restrict__ wde,
                            int n,
                            _Float16* __restrict__ hout,
                            float4* __restrict__ a_src4, float4* __restrict__ a_dst4) {
    __shared__ float agg_lds[4][64];
    int tid = threadIdx.x;
    int lane = tid & 63;
    int wid = tid >> 6;
    int t = lane >> 3, g = lane & 7;
    const half8* hs8 = (const half8*)hs_in;
    float wreg[64];
#pragma unroll
    for (int k = 0; k < 64; ++k) wreg[k] = W[k * 64 + lane];
    float bl = b[lane];
    float4 we, wd;
    if (LAST) {
        we = ((const float4*)wse)[lane];
        wd = ((const float4*)wde)[lane];
    }
    int nw = gridDim.x * 4;
    for (int node = blockIdx.x * 4 + wid; node < n; node += nw) {
        int beg = row_ptr[node], end = row_ptr[node + 1];
        int deg = end - beg;
        half8 sv = hs8[node * 8 + t];
        float ac[8];
#pragma unroll
        for (int c = 0; c < 8; ++c) ac[c] = (g == 0) ? (float)sv[c] : 0.f;
        for (int base = 0; base < deg; base += 64) {
            int cs = col_src[min(beg + base + lane, end - 1)];
            int lim = min(deg - base, 64);
            // full (all-valid) 8-slot body: no per-slot guard needed
            auto bodyF = [&](int eo8) {
                int s = __shfl(cs, eo8 + g);
                half8 v = hs8[s * 8 + t];
#pragma unroll
                for (int c = 0; c < 8; ++c) ac[c] += (float)v[c];
            };
            // guarded 8-slot body for the tail
            auto bodyG = [&](int eo8) {
                int eo = eo8 + g;
                int s = __shfl(cs, eo);
                half8 v = hs8[s * 8 + t];
                if (eo < lim) {
#pragma unroll
                    for (int c = 0; c < 8; ++c) ac[c] += (float)v[c];
                }
            };
            int eo8 = 0;
            for (; eo8 + 16 <= lim; eo8 += 16) { bodyF(eo8); bodyF(eo8 + 8); }
            if (eo8 < lim) {
                bodyG(eo8);
                eo8 += 8;
                if (eo8 < lim) bodyG(eo8);
            }
        }
        float di = dinv[node];
#pragma unroll
        for (int c = 0; c < 8; ++c) ac[c] = red8(ac[c]) * di;
        if (g == 0) {
            *(float4*)&agg_lds[wid][t * 8]     = make_float4(ac[0], ac[1], ac[2], ac[3]);
            *(float4*)&agg_lds[wid][t * 8 + 4] = make_float4(ac[4], ac[5], ac[6], ac[7]);
        }
        __asm__ volatile("s_waitcnt lgkmcnt(0)" ::: "memory");
        float sum = bl;
#pragma unroll
        for (int k4 = 0; k4 < 16; ++k4) {
            float4 a4 = *(const float4*)&agg_lds[wid][k4 * 4];
            sum = fmaf(a4.x, wreg[k4 * 4 + 0], sum);
            sum = fmaf(a4.y, wreg[k4 * 4 + 1], sum);
            sum = fmaf(a4.z, wreg[k4 * 4 + 2], sum);
            sum = fmaf(a4.w, wreg[k4 * 4 + 3], sum);
        }
        float hprev = rdinv[node] * (float)sv[g];   // sv[g] == hs_in[node*64+lane]
        float hv = hprev + fmaxf(sum, 0.f);
        if (!LAST) {
            hout[node * 64 + lane] = (_Float16)(di * hv);
        } else {
            hout[node * 64 + lane] = (_Float16)hv;
            float vs0 = red64(hv * we.x), vs1 = red64(hv * we.y);
            float vs2 = red64(hv * we.z), vs3 = red64(hv * we.w);
            float vd0 = red64(hv * wd.x), vd1 = red64(hv * wd.y);
            float vd2 = red64(hv * wd.z), vd3 = red64(hv * wd.w);
            if (lane == 0) {
                a_src4[node] = make_float4(vs0, vs1, vs2, vs3);
                a_dst4[node] = make_float4(vd0, vd1, vd2, vd3);
            }
        }
    }
}

// ---- GAT aggregate: LDS-staged per-edge weights, fp16 agg rows ------------
//
// Per 64-edge batch each lane computes its OWN edge's 4 exp weights once
// (validity folded in as w=0) and stages {src, float4 w} in per-wave LDS.
// Inner loop per 8-slot group: ds_read_b32 + ds_read_b128 + 16B h gather +
// 32 FMA. No exp/leaky/cndmask in the hot path; no redundant a_src4 loads.

__global__ void gat_agg(const _Float16* __restrict__ h3,
                        const float4* __restrict__ a_src4, const float4* __restrict__ a_dst4,
                        const int* __restrict__ row_ptr, const int* __restrict__ col_src,
                        int n, _Float16* __restrict__ aggout) {
    __shared__ float4 w_lds[4][64];   // per-wave staged edge weights
    __shared__ int    s_lds[4][64];   // per-wave staged edge sources
    int tid = threadIdx.x, lane = tid & 63, wid = tid >> 6;
    int node = blockIdx.x * 4 + wid;
    if (node >= n) return;
    int t = lane >> 3, g = lane & 7;
    const half8* h38 = (const half8*)h3;

    float4 ad = a_dst4[node];
    half8 hself = h38[node * 8 + t];
    float A[4][8], dh[4];
    {
        float4 asf = a_src4[node];
        float w0 = __expf(leaky02(asf.x + ad.x));
        float w1 = __expf(leaky02(asf.y + ad.y));
        float w2 = __expf(leaky02(asf.z + ad.z));
        float w3 = __expf(leaky02(asf.w + ad.w));
        float m0 = (g == 0) ? 1.f : 0.f;
        dh[0] = m0 * w0; dh[1] = m0 * w1; dh[2] = m0 * w2; dh[3] = m0 * w3;
#pragma unroll
        for (int c = 0; c < 8; ++c) {
            float hvc = (float)hself[c];
            A[0][c] = dh[0] * hvc;
            A[1][c] = dh[1] * hvc;
            A[2][c] = dh[2] * hvc;
            A[3][c] = dh[3] * hvc;
        }
    }
    int beg = row_ptr[node], end = row_ptr[node + 1];
    int deg = end - beg;
    for (int base = 0; base < deg; base += 64) {
        // stage: each lane handles ONE edge -> 4 expf per 64 edges (was x8)
        int cs = col_src[min(beg + base + lane, end - 1)];
        float4 as = a_src4[cs];
        float valid = (base + lane < deg) ? 1.f : 0.f;
        float4 wv;
        wv.x = valid * __expf(leaky02(as.x + ad.x));
        wv.y = valid * __expf(leaky02(as.y + ad.y));
        wv.z = valid * __expf(leaky02(as.z + ad.z));
        wv.w = valid * __expf(leaky02(as.w + ad.w));
        w_lds[wid][lane] = wv;
        s_lds[wid][lane] = cs;
        // same-wave LDS is serviced in order; asm acts as compiler barrier
        __asm__ volatile("s_waitcnt lgkmcnt(0)" ::: "memory");
        int lim = min(deg - base, 64);
        auto body = [&](int eo8) {
            int eo = eo8 + g;
            int s = s_lds[wid][eo];
            float4 w4 = w_lds[wid][eo];
            half8 hv = h38[s * 8 + t];
#pragma unroll
            for (int c = 0; c < 8; ++c) {
                float hvc = (float)hv[c];
                A[0][c] = fmaf(w4.x, hvc, A[0][c]);
                A[1][c] = fmaf(w4.y, hvc, A[1][c]);
                A[2][c] = fmaf(w4.z, hvc, A[2][c]);
                A[3][c] = fmaf(w4.w, hvc, A[3][c]);
            }
            dh[0] += w4.x; dh[1] += w4.y; dh[2] += w4.z; dh[3] += w4.w;
        };
        int eo8 = 0;
        for (; eo8 + 16 <= lim; eo8 += 16) { body(eo8); body(eo8 + 8); }
        if (eo8 < lim) {
            body(eo8);                       // padded slots have w=0
            eo8 += 8;
            if (eo8 < lim) body(eo8);
        }
    }
#pragma unroll
    for (int h = 0; h < 4; ++h) {
#pragma unroll
        for (int c = 0; c < 8; ++c) A[h][c] = red8(A[h][c]);
        dh[h] = red8(dh[h]);
    }
    float r0 = 1.f / (dh[0] + 1e-16f);
    float r1 = 1.f / (dh[1] + 1e-16f);
    float r2 = 1.f / (dh[2] + 1e-16f);
    float r3 = 1.f / (dh[3] + 1e-16f);
    if (g < 4) {
        float r = sel4(g, r0, r1, r2, r3);
        half8 hv;
#pragma unroll
        for (int c = 0; c < 8; ++c)
            hv[c] = (_Float16)(sel4(g, A[0][c], A[1][c], A[2][c], A[3][c]) * r);
        *(half8*)(aggout + (size_t)node * 256 + g * 64 + t * 8) = hv;
    }
}

// ---- MLP: Ccomb rows in VGPRs (4-wave split), fp16 agg scalar loads -------

__global__ __launch_bounds__(256) void mlp_kernel(
        const _Float16* __restrict__ agg,
        const float* __restrict__ Ccomb, const float* __restrict__ bcomb,
        const float* __restrict__ wc2, const float* __restrict__ bc2,
        int n, float* __restrict__ out) {
    __shared__ float part[4][4][64];   // [node-in-chunk][wave][lane]
    int tid = threadIdx.x;
    int lane = tid & 63;
    int w = __builtin_amdgcn_readfirstlane(tid >> 6);
    float creg[64];
#pragma unroll
    for (int i = 0; i < 64; ++i) creg[i] = Ccomb[(w * 64 + i) * 64 + lane];
    float bz = bcomb[lane];
    float w20 = wc2[lane * 3 + 0], w21 = wc2[lane * 3 + 1], w22 = wc2[lane * 3 + 2];
    float bb0 = bc2[0], bb1 = bc2[1], bb2 = bc2[2];
    int nchunks = (n + 3) >> 2;
    for (int ch = blockIdx.x; ch < nchunks; ch += gridDim.x) {
        int base = ch * 4;
#pragma unroll
        for (int j = 0; j < 4; ++j) {
            int li = min(base + j, n - 1);
            const half2v* a2 = (const half2v*)(agg + (size_t)li * 256 + w * 64);
            float p = 0.f;
#pragma unroll
            for (int i = 0; i < 32; ++i) {
                half2v hv = a2[i];
                p = fmaf((float)hv[0], creg[2 * i], p);
                p = fmaf((float)hv[1], creg[2 * i + 1], p);
            }
            part[j][w][lane] = p;
        }
        __syncthreads();
        int li = base + w;
        if (li < n) {
            float z = bz + part[w][0][lane] + part[w][1][lane]
                         + part[w][2][lane] + part[w][3][lane];
            z = fmaxf(z, 0.f);
            float p0 = red64(z * w20);
            float p1 = red64(z * w21);
            float p2 = red64(z * w22);
            if (lane == 0) {
                float e0 = p0 + bb0, e1 = p1 + bb1, e2 = p2 + bb2;
                float mx = fmaxf(e0, fmaxf(e1, e2));
                float lse = mx + logf(expf(e0 - mx) + expf(e1 - mx) + expf(e2 - mx));
                out[li * 3 + 0] = e0 - lse;
                out[li * 3 + 1] = e1 - lse;
                out[li * 3 + 2] = e2 - lse;
            }
        }
        __syncthreads();
    }
}

// ---------------------------------------------------------------------------

extern "C" void kernel_launch(void* const* d_in, const int* in_sizes, int n_in,
                              void* d_out, int out_size, void* d_ws, size_t ws_size,
                              hipStream_t stream) {
    const float* x       = (const float*)d_in[0];
    const int*   ei      = (const int*)d_in[1];
    const float* w1      = (const float*)d_in[2];
    const float* b1      = (const float*)d_in[3];
    const float* w2      = (const float*)d_in[4];
    const float* b2      = (const float*)d_in[5];
    const float* w3      = (const float*)d_in[6];
    const float* b3      = (const float*)d_in[7];
    const float* wg      = (const float*)d_in[8];
    const float* bg      = (const float*)d_in[9];
    const float* att_s   = (const float*)d_in[10];
    const float* att_d   = (const float*)d_in[11];
    const float* wc1     = (const float*)d_in[12];
    const float* bc1     = (const float*)d_in[13];
    const float* wc2     = (const float*)d_in[14];
    const float* bc2     = (const float*)d_in[15];
    float* out = (float*)d_out;

    const int N = in_sizes[0] / 8;
    const int E = in_sizes[1] / 2;
    const int* srcv = ei;
    const int* dstv = ei + E;

    char* ws = (char*)d_ws;
    size_t off = 0;
    auto alloc = [&](size_t bytes) -> char* {
        char* p = ws + off;
        off += (bytes + 255) & ~(size_t)255;
        return p;
    };
    int*      counts    = (int*)alloc((size_t)N * 4);
    int*      row_ptr   = (int*)alloc((size_t)(N + 1) * 4);
    int*      cursor    = (int*)alloc((size_t)N * 4);
    int*      col_src   = (int*)alloc((size_t)E * 4);
    int*      blockSums = (int*)alloc(4096 * 4);
    int*      blockOffs = (int*)alloc(4096 * 4);
    float*    dinv      = (float*)alloc((size_t)N * 4);
    float*    rdinv     = (float*)alloc((size_t)N * 4);
    _Float16* xs        = (_Float16*)alloc((size_t)N * 8 * 2);
    float*    a_src     = (float*)alloc((size_t)N * 16);
    float*    a_dst     = (float*)alloc((size_t)N * 16);
    float*    wse       = (float*)alloc(256 * 4);
    float*    wde       = (float*)alloc(256 * 4);
    float*    Ccomb     = (float*)alloc(256 * 64 * 4);
    float*    bcomb     = (float*)alloc(64 * 4);
    _Float16* bufA      = (_Float16*)alloc((size_t)N * 64 * 2);  // hs1, later h3
    _Float16* bufB      = (_Float16*)alloc((size_t)N * 64 * 2);  // hs2
    _Float16* aggbuf    = (_Float16*)alloc((size_t)N * 256 * 2); // 51.2MB fp16
    _Float16* hs1 = bufA;
    _Float16* hs2 = bufB;
    _Float16* h3  = bufA;   // hs1 dead once layer3 runs
    (void)ws_size; (void)n_in; (void)out_size;

    hipMemsetAsync(counts, 0, (size_t)N * 4, stream);

    const int TPB = 256;
    int range = (N + 7) / 8;
    count_kernel<<<1024, TPB, 0, stream>>>(dstv, E, range, counts);

    int NB = (N + 2047) / 2048;
    scan_pass1<<<NB, TPB, 0, stream>>>(counts, N, blockSums);
    scan_pass2<<<1, 64, 0, stream>>>(blockSums, NB, blockOffs);
    scan_pass3<<<NB, TPB, 0, stream>>>(counts, N, blockOffs, x,
                                       row_ptr, cursor, dinv, rdinv, xs);
    scatter_kernel<<<2048, TPB, 0, stream>>>(srcv, dstv, E, range, cursor, col_src);

    ccomb_kernel<<<257, 64, 0, stream>>>(wg, bg, wc1, bc1, att_s, att_d,
                                         Ccomb, bcomb, wse, wde);

    int gridN = (N + 3) / 4;
    gcn_layer1<<<gridN, TPB, 0, stream>>>((const half8*)xs, w1, b1, row_ptr, col_src,
                                          dinv, N, hs1);
    const int G64 = 2048;   // 8 blocks/CU: lift grid-capped occupancy (was 39%)
    gcn_layer64<false><<<G64, TPB, 0, stream>>>(hs1, w2, b2, row_ptr, col_src,
                                                dinv, rdinv, wse, wde, N, hs2,
                                                nullptr, nullptr);
    gcn_layer64<true><<<G64, TPB, 0, stream>>>(hs2, w3, b3, row_ptr, col_src,
                                               dinv, rdinv, wse, wde, N, h3,
                                               (float4*)a_src, (float4*)a_dst);

    gat_agg<<<gridN, TPB, 0, stream>>>(h3, (const float4*)a_src, (const float4*)a_dst,
                                       row_ptr, col_src, N, aggbuf);
    mlp_kernel<<<1024, TPB, 0, stream>>>(aggbuf, Ccomb, bcomb, wc2, bc2, N, out);
}

// Round 2
// 560.435 us; speedup vs baseline: 1.1526x; 1.1168x over previous
//
#include <hip/hip_runtime.h>
#include <math.h>

// ---------------------------------------------------------------------------
// SpatialGNN: 3x GCN (residual) + 4-head GAT + MLP + log_softmax
// N=100000, E=1600000, IN=8, HID=64, HEADS=4, OUT=3
//
// R12 changes vs R11:
//  - mlp_kernel (103.8us, VALU-bound at 6% HBM) replaced by mlp_mfma:
//    Z = relu(AGG[N,256] @ C[256,64]) on v_mfma_f32_16x16x32_f16.
//    C is split into fp16 hi+lo halves (effective ~22-bit precision, matches
//    the old fp32-C numerics) and pre-swizzled into B-fragment order by
//    ccomb_kernel. Each wave owns one 16-col slice; B frags live in VGPRs;
//    per 16-node tile: 8x16B coalesced A loads + 16 MFMA + red16 epilogue.
//    Memory floor ~8us, compute floor ~1.3us vs 104us VALU version.
// ---------------------------------------------------------------------------

typedef _Float16 half8 __attribute__((ext_vector_type(8)));
typedef _Float16 f16x8 __attribute__((ext_vector_type(8)));
typedef float f32x4 __attribute__((ext_vector_type(4)));

__device__ __forceinline__ float leaky02(float v) { return v > 0.f ? v : 0.2f * v; }

// ---- cross-lane reduction helpers (DPP/swizzle; minimize DS-pipe ops) -----

template <int CTRL>
__device__ __forceinline__ float dpp_add(float v) {
    int iv = __builtin_bit_cast(int, v);
    int r = __builtin_amdgcn_update_dpp(iv, iv, CTRL, 0xF, 0xF, false);
    return v + __builtin_bit_cast(float, r);
}
template <int OFF>
__device__ __forceinline__ float swz_add(float v) {
    int r = __builtin_amdgcn_ds_swizzle(__builtin_bit_cast(int, v), OFF);
    return v + __builtin_bit_cast(float, r);
}
__device__ __forceinline__ float red8(float v) {
    v = dpp_add<0xB1>(v);     // xor1
    v = dpp_add<0x4E>(v);     // xor2
    v = swz_add<0x101F>(v);   // xor4
    return v;
}
__device__ __forceinline__ float red16(float v) {
    v = dpp_add<0xB1>(v);     // xor1
    v = dpp_add<0x4E>(v);     // xor2
    v = swz_add<0x101F>(v);   // xor4
    v = dpp_add<0x128>(v);    // row_ror:8 -> completes 16-lane sum
    return v;
}
__device__ __forceinline__ float red64(float v) {
    v = dpp_add<0xB1>(v);
    v = dpp_add<0x4E>(v);
    v = swz_add<0x101F>(v);
    v = dpp_add<0x128>(v);    // xor8: row_ror:8
    v = swz_add<0x401F>(v);   // xor16
    v = v + __shfl_xor(v, 32);
    return v;
}
__device__ __forceinline__ float sel4(int g, float v0, float v1, float v2, float v3) {
    return g == 0 ? v0 : g == 1 ? v1 : g == 2 ? v2 : v3;
}

// ---- CSR build ------------------------------------------------------------

// XCD-range-filtered count: group blockIdx&7 counts only its dst range.
__global__ void count_kernel(const int* __restrict__ dst, int E, int range,
                             int* __restrict__ counts) {
    int grp = blockIdx.x & 7;
    int nlo = grp * range;
    int nhi = nlo + range;
    int nblk = gridDim.x >> 3;
    int c = blockIdx.x >> 3;
    int stride = nblk * blockDim.x;
    for (int e = c * blockDim.x + threadIdx.x; e < E; e += stride) {
        int d = dst[e];
        if (d >= nlo && d < nhi) atomicAdd(&counts[d], 1);
    }
}

__global__ void scan_pass1(const int* __restrict__ counts, int n, int* __restrict__ blockSums) {
    __shared__ int sh[256];
    int base = blockIdx.x * 2048;
    int tid = threadIdx.x;
    int s = 0;
#pragma unroll
    for (int j = 0; j < 8; ++j) {
        int idx = base + tid * 8 + j;
        if (idx < n) s += counts[idx];
    }
    sh[tid] = s;
    __syncthreads();
    for (int off = 128; off > 0; off >>= 1) {
        if (tid < off) sh[tid] += sh[tid + off];
        __syncthreads();
    }
    if (tid == 0) blockSums[blockIdx.x] = sh[0];
}

__global__ void scan_pass2(const int* __restrict__ blockSums, int nb, int* __restrict__ blockOffs) {
    if (threadIdx.x == 0 && blockIdx.x == 0) {
        int run = 0;
        for (int i = 0; i < nb; ++i) { blockOffs[i] = run; run += blockSums[i]; }
    }
}

__global__ void scan_pass3(const int* __restrict__ counts, int n,
                           const int* __restrict__ blockOffs,
                           const float* __restrict__ x,
                           int* __restrict__ row_ptr, int* __restrict__ cursor,
                           float* __restrict__ dinv, float* __restrict__ rdinv,
                           _Float16* __restrict__ xs) {
    __shared__ int sh[256];
    int base = blockIdx.x * 2048;
    int tid = threadIdx.x;
    int cnt[8];
    int local = 0;
#pragma unroll
    for (int j = 0; j < 8; ++j) {
        int idx = base + tid * 8 + j;
        cnt[j] = (idx < n) ? counts[idx] : 0;
        local += cnt[j];
    }
    sh[tid] = local;
    __syncthreads();
    for (int off = 1; off < 256; off <<= 1) {
        int v = (tid >= off) ? sh[tid - off] : 0;
        __syncthreads();
        sh[tid] += v;
        __syncthreads();
    }
    int run = blockOffs[blockIdx.x] + sh[tid] - local;
#pragma unroll
    for (int j = 0; j < 8; ++j) {
        int idx = base + tid * 8 + j;
        if (idx < n) {
            row_ptr[idx] = run;
            cursor[idx] = run;
            float dv = rsqrtf((float)(cnt[j] + 1));
            dinv[idx] = dv;
            rdinv[idx] = sqrtf((float)(cnt[j] + 1));
#pragma unroll
            for (int t = 0; t < 8; ++t) xs[idx * 8 + t] = (_Float16)(dv * x[idx * 8 + t]);
            run += cnt[j];
            if (idx == n - 1) row_ptr[n] = run;
        }
    }
}

// XCD-range-filtered scatter (R9, kept): col_src/cursor writes stay XCD-local.
__global__ void scatter_kernel(const int* __restrict__ src, const int* __restrict__ dst,
                               int E, int range,
                               int* __restrict__ cursor, int* __restrict__ col_src) {
    int grp = blockIdx.x & 7;
    int nlo = grp * range;
    int nhi = nlo + range;
    int nblk = gridDim.x >> 3;
    int c = blockIdx.x >> 3;
    int stride = nblk * blockDim.x;
    for (int e = c * blockDim.x + threadIdx.x; e < E; e += stride) {
        int d = dst[e];
        if (d >= nlo && d < nhi) {
            int pos = atomicAdd(&cursor[d], 1);
            col_src[pos] = src[e];
        }
    }
}

// ---- weight precompute: Ccomb (fp16 split, B-frag order) + attn vectors ---
//
// CcombP layout (64KB): fragment f = p*32 + ct*8 + kt  (p: 0=hi, 1=lo),
// within fragment: lane l (0..63) * 8 halfs + elem e.
// B-fragment mapping for v_mfma_f32_16x16x32_f16:
//   col(n) = ct*16 + (l&15),  k = kt*32 + (l>>4)*8 + e.

__global__ void ccomb_kernel(const float* __restrict__ Wg, const float* __restrict__ bg,
                             const float* __restrict__ wc1, const float* __restrict__ bc1,
                             const float* __restrict__ att_src, const float* __restrict__ att_dst,
                             _Float16* __restrict__ CcombP, float* __restrict__ bcomb,
                             float* __restrict__ wse, float* __restrict__ wde) {
    int bid = blockIdx.x;   // 0..256
    int j = threadIdx.x;    // 64 threads
    if (bid < 256) {
        int i = bid;        // k index (agg channel)
        float s = 0.f;
        for (int c = 0; c < 64; ++c)
            s += Wg[(i & 63) * 256 + (i >> 6) * 64 + c] * wc1[((i >> 6) * 64 + c) * 64 + j];
        // NOTE: i = h*64+k ordering must match agg layout: agg channel
        // index = g*64 + t*8 + c with h=g, so channel i -> h = i>>6, k-in-head
        // = i&63. Wg row = k-in-head (wc1-input-channel = h*64+c).
        _Float16 hi = (_Float16)s;
        _Float16 lo = (_Float16)(s - (float)hi);
        int kt = i >> 5, l = (((i >> 3) & 3) << 4) | (j & 15), e = i & 7, ct = j >> 4;
        CcombP[(ct * 8 + kt) * 512 + l * 8 + e] = hi;
        CcombP[(32 + ct * 8 + kt) * 512 + l * 8 + e] = lo;
    } else {
        float s = bc1[j];
        for (int i = 0; i < 256; ++i) s += bg[i] * wc1[i * 64 + j];
        bcomb[j] = s;
#pragma unroll
        for (int h = 0; h < 4; ++h) {
            float ss = 0.f, sd = 0.f;
            for (int c = 0; c < 64; ++c) {
                float w = Wg[j * 256 + h * 64 + c];
                ss += w * att_src[h * 64 + c];
                sd += w * att_dst[h * 64 + c];
            }
            wse[j * 4 + h] = ss;
            wde[j * 4 + h] = sd;
        }
    }
}

// ---- GCN layer 1: one edge per lane (16B half8 row) -----------------------

__global__ void gcn_layer1(const half8* __restrict__ xs8,
                           const float* __restrict__ W1, const float* __restrict__ b1,
                           const int* __restrict__ row_ptr, const int* __restrict__ col_src,
                           const float* __restrict__ dinv, int n,
                           _Float16* __restrict__ hs1) {
    int tid = threadIdx.x, lane = tid & 63, wid = tid >> 6;
    int node = blockIdx.x * 4 + wid;
    if (node >= n) return;
    int beg = row_ptr[node], end = row_ptr[node + 1];
    int deg = end - beg;
    float acc[8] = {0.f, 0.f, 0.f, 0.f, 0.f, 0.f, 0.f, 0.f};
    for (int base = 0; base < deg; base += 64) {
        int cs = col_src[min(beg + base + lane, end - 1)];
        half8 v = xs8[cs];
        if (base + lane < deg) {
#pragma unroll
            for (int c = 0; c < 8; ++c) acc[c] += (float)v[c];
        }
    }
#pragma unroll
    for (int c = 0; c < 8; ++c) acc[c] = red64(acc[c]);
    half8 sv = xs8[node];
    float di = dinv[node];
    float agg[8];
#pragma unroll
    for (int c = 0; c < 8; ++c) agg[c] = (acc[c] + (float)sv[c]) * di;
    float sum = b1[lane];
#pragma unroll
    for (int k = 0; k < 8; ++k) sum = fmaf(agg[k], W1[k * 64 + lane], sum);
    hs1[node * 64 + lane] = (_Float16)(di * fmaxf(sum, 0.f));
}

// ---- GCN layer 2/3: g=lane&7 edge slots, t=lane>>3 channel chunks ---------

template <bool LAST>
__global__ void gcn_layer64(const _Float16* __restrict__ hs_in,
                            const float* __restrict__ W, const float* __restrict__ b,
                            const int* __restrict__ row_ptr, const int* __restrict__ col_src,
                            const float* __restrict__ dinv, const float* __restrict__ rdinv,
                            const float* __restrict__ wse, const float* __restrict__ wde,
                            int n,
                            _Float16* __restrict__ hout,
                            float4* __restrict__ a_src4, float4* __restrict__ a_dst4) {
    __shared__ float agg_lds[4][64];
    int tid = threadIdx.x;
    int lane = tid & 63;
    int wid = tid >> 6;
    int t = lane >> 3, g = lane & 7;
    const half8* hs8 = (const half8*)hs_in;
    float wreg[64];
#pragma unroll
    for (int k = 0; k < 64; ++k) wreg[k] = W[k * 64 + lane];
    float bl = b[lane];
    float4 we, wd;
    if (LAST) {
        we = ((const float4*)wse)[lane];
        wd = ((const float4*)wde)[lane];
    }
    int nw = gridDim.x * 4;
    for (int node = blockIdx.x * 4 + wid; node < n; node += nw) {
        int beg = row_ptr[node], end = row_ptr[node + 1];
        int deg = end - beg;
        half8 sv = hs8[node * 8 + t];
        float ac[8];
#pragma unroll
        for (int c = 0; c < 8; ++c) ac[c] = (g == 0) ? (float)sv[c] : 0.f;
        for (int base = 0; base < deg; base += 64) {
            int cs = col_src[min(beg + base + lane, end - 1)];
            int lim = min(deg - base, 64);
            // full (all-valid) 8-slot body: no per-slot guard needed
            auto bodyF = [&](int eo8) {
                int s = __shfl(cs, eo8 + g);
                half8 v = hs8[s * 8 + t];
#pragma unroll
                for (int c = 0; c < 8; ++c) ac[c] += (float)v[c];
            };
            // guarded 8-slot body for the tail
            auto bodyG = [&](int eo8) {
                int eo = eo8 + g;
                int s = __shfl(cs, eo);
                half8 v = hs8[s * 8 + t];
                if (eo < lim) {
#pragma unroll
                    for (int c = 0; c < 8; ++c) ac[c] += (float)v[c];
                }
            };
            int eo8 = 0;
            for (; eo8 + 16 <= lim; eo8 += 16) { bodyF(eo8); bodyF(eo8 + 8); }
            if (eo8 < lim) {
                bodyG(eo8);
                eo8 += 8;
                if (eo8 < lim) bodyG(eo8);
            }
        }
        float di = dinv[node];
#pragma unroll
        for (int c = 0; c < 8; ++c) ac[c] = red8(ac[c]) * di;
        if (g == 0) {
            *(float4*)&agg_lds[wid][t * 8]     = make_float4(ac[0], ac[1], ac[2], ac[3]);
            *(float4*)&agg_lds[wid][t * 8 + 4] = make_float4(ac[4], ac[5], ac[6], ac[7]);
        }
        __asm__ volatile("s_waitcnt lgkmcnt(0)" ::: "memory");
        float sum = bl;
#pragma unroll
        for (int k4 = 0; k4 < 16; ++k4) {
            float4 a4 = *(const float4*)&agg_lds[wid][k4 * 4];
            sum = fmaf(a4.x, wreg[k4 * 4 + 0], sum);
            sum = fmaf(a4.y, wreg[k4 * 4 + 1], sum);
            sum = fmaf(a4.z, wreg[k4 * 4 + 2], sum);
            sum = fmaf(a4.w, wreg[k4 * 4 + 3], sum);
        }
        float hprev = rdinv[node] * (float)sv[g];   // sv[g] == hs_in[node*64+lane]
        float hv = hprev + fmaxf(sum, 0.f);
        if (!LAST) {
            hout[node * 64 + lane] = (_Float16)(di * hv);
        } else {
            hout[node * 64 + lane] = (_Float16)hv;
            float vs0 = red64(hv * we.x), vs1 = red64(hv * we.y);
            float vs2 = red64(hv * we.z), vs3 = red64(hv * we.w);
            float vd0 = red64(hv * wd.x), vd1 = red64(hv * wd.y);
            float vd2 = red64(hv * wd.z), vd3 = red64(hv * wd.w);
            if (lane == 0) {
                a_src4[node] = make_float4(vs0, vs1, vs2, vs3);
                a_dst4[node] = make_float4(vd0, vd1, vd2, vd3);
            }
        }
    }
}

// ---- GAT aggregate: LDS-staged per-edge weights, fp16 agg rows ------------

__global__ void gat_agg(const _Float16* __restrict__ h3,
                        const float4* __restrict__ a_src4, const float4* __restrict__ a_dst4,
                        const int* __restrict__ row_ptr, const int* __restrict__ col_src,
                        int n, _Float16* __restrict__ aggout) {
    __shared__ float4 w_lds[4][64];   // per-wave staged edge weights
    __shared__ int    s_lds[4][64];   // per-wave staged edge sources
    int tid = threadIdx.x, lane = tid & 63, wid = tid >> 6;
    int node = blockIdx.x * 4 + wid;
    if (node >= n) return;
    int t = lane >> 3, g = lane & 7;
    const half8* h38 = (const half8*)h3;

    float4 ad = a_dst4[node];
    half8 hself = h38[node * 8 + t];
    float A[4][8], dh[4];
    {
        float4 asf = a_src4[node];
        float w0 = __expf(leaky02(asf.x + ad.x));
        float w1 = __expf(leaky02(asf.y + ad.y));
        float w2 = __expf(leaky02(asf.z + ad.z));
        float w3 = __expf(leaky02(asf.w + ad.w));
        float m0 = (g == 0) ? 1.f : 0.f;
        dh[0] = m0 * w0; dh[1] = m0 * w1; dh[2] = m0 * w2; dh[3] = m0 * w3;
#pragma unroll
        for (int c = 0; c < 8; ++c) {
            float hvc = (float)hself[c];
            A[0][c] = dh[0] * hvc;
            A[1][c] = dh[1] * hvc;
            A[2][c] = dh[2] * hvc;
            A[3][c] = dh[3] * hvc;
        }
    }
    int beg = row_ptr[node], end = row_ptr[node + 1];
    int deg = end - beg;
    for (int base = 0; base < deg; base += 64) {
        // stage: each lane handles ONE edge -> 4 expf per 64 edges
        int cs = col_src[min(beg + base + lane, end - 1)];
        float4 as = a_src4[cs];
        float valid = (base + lane < deg) ? 1.f : 0.f;
        float4 wv;
        wv.x = valid * __expf(leaky02(as.x + ad.x));
        wv.y = valid * __expf(leaky02(as.y + ad.y));
        wv.z = valid * __expf(leaky02(as.z + ad.z));
        wv.w = valid * __expf(leaky02(as.w + ad.w));
        w_lds[wid][lane] = wv;
        s_lds[wid][lane] = cs;
        __asm__ volatile("s_waitcnt lgkmcnt(0)" ::: "memory");
        int lim = min(deg - base, 64);
        auto body = [&](int eo8) {
            int eo = eo8 + g;
            int s = s_lds[wid][eo];
            float4 w4 = w_lds[wid][eo];
            half8 hv = h38[s * 8 + t];
#pragma unroll
            for (int c = 0; c < 8; ++c) {
                float hvc = (float)hv[c];
                A[0][c] = fmaf(w4.x, hvc, A[0][c]);
                A[1][c] = fmaf(w4.y, hvc, A[1][c]);
                A[2][c] = fmaf(w4.z, hvc, A[2][c]);
                A[3][c] = fmaf(w4.w, hvc, A[3][c]);
            }
            dh[0] += w4.x; dh[1] += w4.y; dh[2] += w4.z; dh[3] += w4.w;
        };
        int eo8 = 0;
        for (; eo8 + 16 <= lim; eo8 += 16) { body(eo8); body(eo8 + 8); }
        if (eo8 < lim) {
            body(eo8);                       // padded slots have w=0
            eo8 += 8;
            if (eo8 < lim) body(eo8);
        }
    }
#pragma unroll
    for (int h = 0; h < 4; ++h) {
#pragma unroll
        for (int c = 0; c < 8; ++c) A[h][c] = red8(A[h][c]);
        dh[h] = red8(dh[h]);
    }
    float r0 = 1.f / (dh[0] + 1e-16f);
    float r1 = 1.f / (dh[1] + 1e-16f);
    float r2 = 1.f / (dh[2] + 1e-16f);
    float r3 = 1.f / (dh[3] + 1e-16f);
    if (g < 4) {
        float r = sel4(g, r0, r1, r2, r3);
        half8 hv;
#pragma unroll
        for (int c = 0; c < 8; ++c)
            hv[c] = (_Float16)(sel4(g, A[0][c], A[1][c], A[2][c], A[3][c]) * r);
        *(half8*)(aggout + (size_t)node * 256 + g * 64 + t * 8) = hv;
    }
}

// ---- MLP on matrix cores: Z = relu(AGG @ C) then 64->3 + log_softmax ------
//
// Wave w owns output cols [w*16, w*16+16). B frags (hi+lo x 8 kt) in VGPRs.
// Per 16-node tile: 8x16B A loads (row = tileBase + (lane&15),
// k = kt*32 + (lane>>4)*8), 16 MFMA into f32x4 acc; epilogue: 12 red16 per
// wave + cross-wave LDS combine + log_softmax.

__global__ __launch_bounds__(256) void mlp_mfma(
        const _Float16* __restrict__ agg,
        const _Float16* __restrict__ CP,
        const float* __restrict__ bcomb,
        const float* __restrict__ wc2, const float* __restrict__ bc2,
        int n, float* __restrict__ out) {
    __shared__ float part[4][16][3];
    int tid = threadIdx.x;
    int lane = tid & 63;
    int w = __builtin_amdgcn_readfirstlane(tid >> 6);   // ct slice
    int c16 = lane & 15, hi = lane >> 4;

    f16x8 bh[8], blo[8];
#pragma unroll
    for (int kt = 0; kt < 8; ++kt) {
        bh[kt]  = *(const f16x8*)(CP + (size_t)(w * 8 + kt) * 512 + lane * 8);
        blo[kt] = *(const f16x8*)(CP + (size_t)(32 + w * 8 + kt) * 512 + lane * 8);
    }
    int col = w * 16 + c16;
    float bc  = bcomb[col];
    float w20 = wc2[col * 3 + 0], w21 = wc2[col * 3 + 1], w22 = wc2[col * 3 + 2];
    float bb0 = bc2[0], bb1 = bc2[1], bb2 = bc2[2];

    int ntiles = (n + 15) >> 4;
    for (int tile = blockIdx.x; tile < ntiles; tile += gridDim.x) {
        int rowb = tile * 16;
        int row = min(rowb + c16, n - 1);
        const _Float16* ap = agg + (size_t)row * 256 + hi * 8;
        f16x8 a[8];
#pragma unroll
        for (int kt = 0; kt < 8; ++kt) a[kt] = *(const f16x8*)(ap + kt * 32);
        f32x4 acc = {0.f, 0.f, 0.f, 0.f};
#pragma unroll
        for (int kt = 0; kt < 8; ++kt) {
            acc = __builtin_amdgcn_mfma_f32_16x16x32_f16(a[kt], bh[kt],  acc, 0, 0, 0);
            acc = __builtin_amdgcn_mfma_f32_16x16x32_f16(a[kt], blo[kt], acc, 0, 0, 0);
        }
        // acc[r]: node row = hi*4 + r, col = w*16 + c16
        float pr[4][3];
#pragma unroll
        for (int r = 0; r < 4; ++r) {
            float z = fmaxf(acc[r] + bc, 0.f);
            pr[r][0] = red16(z * w20);
            pr[r][1] = red16(z * w21);
            pr[r][2] = red16(z * w22);
        }
        if (c16 == 0) {
#pragma unroll
            for (int r = 0; r < 4; ++r) {
                part[w][hi * 4 + r][0] = pr[r][0];
                part[w][hi * 4 + r][1] = pr[r][1];
                part[w][hi * 4 + r][2] = pr[r][2];
            }
        }
        __syncthreads();
        if (tid < 16) {
            int node = rowb + tid;
            if (node < n) {
                float e0 = part[0][tid][0] + part[1][tid][0] + part[2][tid][0] + part[3][tid][0] + bb0;
                float e1 = part[0][tid][1] + part[1][tid][1] + part[2][tid][1] + part[3][tid][1] + bb1;
                float e2 = part[0][tid][2] + part[1][tid][2] + part[2][tid][2] + part[3][tid][2] + bb2;
                float mx = fmaxf(e0, fmaxf(e1, e2));
                float lse = mx + logf(expf(e0 - mx) + expf(e1 - mx) + expf(e2 - mx));
                out[(size_t)node * 3 + 0] = e0 - lse;
                out[(size_t)node * 3 + 1] = e1 - lse;
                out[(size_t)node * 3 + 2] = e2 - lse;
            }
        }
        __syncthreads();
    }
}

// ---------------------------------------------------------------------------

extern "C" void kernel_launch(void* const* d_in, const int* in_sizes, int n_in,
                              void* d_out, int out_size, void* d_ws, size_t ws_size,
                              hipStream_t stream) {
    const float* x       = (const float*)d_in[0];
    const int*   ei      = (const int*)d_in[1];
    const float* w1      = (const float*)d_in[2];
    const float* b1      = (const float*)d_in[3];
    const float* w2      = (const float*)d_in[4];
    const float* b2      = (const float*)d_in[5];
    const float* w3      = (const float*)d_in[6];
    const float* b3      = (const float*)d_in[7];
    const float* wg      = (const float*)d_in[8];
    const float* bg      = (const float*)d_in[9];
    const float* att_s   = (const float*)d_in[10];
    const float* att_d   = (const float*)d_in[11];
    const float* wc1     = (const float*)d_in[12];
    const float* bc1     = (const float*)d_in[13];
    const float* wc2     = (const float*)d_in[14];
    const float* bc2     = (const float*)d_in[15];
    float* out = (float*)d_out;

    const int N = in_sizes[0] / 8;
    const int E = in_sizes[1] / 2;
    const int* srcv = ei;
    const int* dstv = ei + E;

    char* ws = (char*)d_ws;
    size_t off = 0;
    auto alloc = [&](size_t bytes) -> char* {
        char* p = ws + off;
        off += (bytes + 255) & ~(size_t)255;
        return p;
    };
    int*      counts    = (int*)alloc((size_t)N * 4);
    int*      row_ptr   = (int*)alloc((size_t)(N + 1) * 4);
    int*      cursor    = (int*)alloc((size_t)N * 4);
    int*      col_src   = (int*)alloc((size_t)E * 4);
    int*      blockSums = (int*)alloc(4096 * 4);
    int*      blockOffs = (int*)alloc(4096 * 4);
    float*    dinv      = (float*)alloc((size_t)N * 4);
    float*    rdinv     = (float*)alloc((size_t)N * 4);
    _Float16* xs        = (_Float16*)alloc((size_t)N * 8 * 2);
    float*    a_src     = (float*)alloc((size_t)N * 16);
    float*    a_dst     = (float*)alloc((size_t)N * 16);
    float*    wse       = (float*)alloc(256 * 4);
    float*    wde       = (float*)alloc(256 * 4);
    _Float16* CcombP    = (_Float16*)alloc(64 * 1024);           // fp16 hi+lo B-frags
    float*    bcomb     = (float*)alloc(64 * 4);
    _Float16* bufA      = (_Float16*)alloc((size_t)N * 64 * 2);  // hs1, later h3
    _Float16* bufB      = (_Float16*)alloc((size_t)N * 64 * 2);  // hs2
    _Float16* aggbuf    = (_Float16*)alloc((size_t)N * 256 * 2); // 51.2MB fp16
    _Float16* hs1 = bufA;
    _Float16* hs2 = bufB;
    _Float16* h3  = bufA;   // hs1 dead once layer3 runs
    (void)ws_size; (void)n_in; (void)out_size;

    hipMemsetAsync(counts, 0, (size_t)N * 4, stream);

    const int TPB = 256;
    int range = (N + 7) / 8;
    count_kernel<<<1024, TPB, 0, stream>>>(dstv, E, range, counts);

    int NB = (N + 2047) / 2048;
    scan_pass1<<<NB, TPB, 0, stream>>>(counts, N, blockSums);
    scan_pass2<<<1, 64, 0, stream>>>(blockSums, NB, blockOffs);
    scan_pass3<<<NB, TPB, 0, stream>>>(counts, N, blockOffs, x,
                                       row_ptr, cursor, dinv, rdinv, xs);
    scatter_kernel<<<2048, TPB, 0, stream>>>(srcv, dstv, E, range, cursor, col_src);

    ccomb_kernel<<<257, 64, 0, stream>>>(wg, bg, wc1, bc1, att_s, att_d,
                                         CcombP, bcomb, wse, wde);

    int gridN = (N + 3) / 4;
    gcn_layer1<<<gridN, TPB, 0, stream>>>((const half8*)xs, w1, b1, row_ptr, col_src,
                                          dinv, N, hs1);
    const int G64 = 2048;   // 8 blocks/CU: lift grid-capped occupancy (was 39%)
    gcn_layer64<false><<<G64, TPB, 0, stream>>>(hs1, w2, b2, row_ptr, col_src,
                                                dinv, rdinv, wse, wde, N, hs2,
                                                nullptr, nullptr);
    gcn_layer64<true><<<G64, TPB, 0, stream>>>(hs2, w3, b3, row_ptr, col_src,
                                               dinv, rdinv, wse, wde, N, h3,
                                               (float4*)a_src, (float4*)a_dst);

    gat_agg<<<gridN, TPB, 0, stream>>>(h3, (const float4*)a_src, (const float4*)a_dst,
                                       row_ptr, col_src, N, aggbuf);
    mlp_mfma<<<2048, TPB, 0, stream>>>(aggbuf, CcombP, bcomb, wc2, bc2, N, out);
}

// Round 4
// 551.726 us; speedup vs baseline: 1.1708x; 1.0158x over previous
//
#include <hip/hip_runtime.h>
#include <math.h>

// ---------------------------------------------------------------------------
// SpatialGNN: 3x GCN (residual) + 4-head GAT + MLP + log_softmax
// N=100000, E=1600000, IN=8, HID=64, HEADS=4, OUT=3
//
// R14 changes vs R13 (which failed absmax 0.109 — suspect: ds_read_b64_tr_b16
// element-order semantics, the only unproven primitive in R13):
//  - gat_agg MFMA kept, but rebuilt on PROVEN primitives only:
//    * A-frag: weights staged TRANSPOSED (wAT[m][slot], rows 0-3 hi / 4-7 lo)
//      via 8x ds_write_u16; A-frag is one plain ds_read_b128 per lane with
//      the exact A layout mlp_mfma already validated.
//    * B-frag: H tile [32][72] halves, XOR-32B swizzle (ch ^ ((k>>3)<<4),
//      same involution on write+read); 32x ds_read_u16 per lane (compiler
//      pairs to d16/d16_hi). No tr-reads anywhere.
//    * hi rows 0-3 + lo rows 4-7 of ONE MFMA, combined by shfl_xor(16).
//    * logit clamp min(l-m,10) on numerator AND denominator: no fp16
//      overflow on multi-tile nodes; softmax shift-consistent.
// ---------------------------------------------------------------------------

typedef _Float16 half8 __attribute__((ext_vector_type(8)));
typedef _Float16 f16x8 __attribute__((ext_vector_type(8)));
typedef float f32x4 __attribute__((ext_vector_type(4)));

__device__ __forceinline__ float leaky02(float v) { return v > 0.f ? v : 0.2f * v; }

// ---- cross-lane reduction helpers (DPP/swizzle; minimize DS-pipe ops) -----

template <int CTRL>
__device__ __forceinline__ float dpp_add(float v) {
    int iv = __builtin_bit_cast(int, v);
    int r = __builtin_amdgcn_update_dpp(iv, iv, CTRL, 0xF, 0xF, false);
    return v + __builtin_bit_cast(float, r);
}
template <int OFF>
__device__ __forceinline__ float swz_add(float v) {
    int r = __builtin_amdgcn_ds_swizzle(__builtin_bit_cast(int, v), OFF);
    return v + __builtin_bit_cast(float, r);
}
template <int CTRL>
__device__ __forceinline__ float dpp_max(float v) {
    int iv = __builtin_bit_cast(int, v);
    int r = __builtin_amdgcn_update_dpp(iv, iv, CTRL, 0xF, 0xF, false);
    return fmaxf(v, __builtin_bit_cast(float, r));
}
template <int OFF>
__device__ __forceinline__ float swz_max(float v) {
    int r = __builtin_amdgcn_ds_swizzle(__builtin_bit_cast(int, v), OFF);
    return fmaxf(v, __builtin_bit_cast(float, r));
}
__device__ __forceinline__ float red8(float v) {
    v = dpp_add<0xB1>(v);     // xor1
    v = dpp_add<0x4E>(v);     // xor2
    v = swz_add<0x101F>(v);   // xor4
    return v;
}
__device__ __forceinline__ float red16(float v) {
    v = dpp_add<0xB1>(v);
    v = dpp_add<0x4E>(v);
    v = swz_add<0x101F>(v);
    v = dpp_add<0x128>(v);    // row_ror:8 -> completes 16-lane sum
    return v;
}
__device__ __forceinline__ float red64(float v) {
    v = dpp_add<0xB1>(v);
    v = dpp_add<0x4E>(v);
    v = swz_add<0x101F>(v);
    v = dpp_add<0x128>(v);    // xor8: row_ror:8
    v = swz_add<0x401F>(v);   // xor16
    v = v + __shfl_xor(v, 32);
    return v;
}
__device__ __forceinline__ float red64max(float v) {
    v = dpp_max<0xB1>(v);
    v = dpp_max<0x4E>(v);
    v = swz_max<0x101F>(v);
    v = dpp_max<0x128>(v);
    v = swz_max<0x401F>(v);
    v = fmaxf(v, __shfl_xor(v, 32));
    return v;
}

// ---- CSR build ------------------------------------------------------------

// XCD-range-filtered count: group blockIdx&7 counts only its dst range.
__global__ void count_kernel(const int* __restrict__ dst, int E, int range,
                             int* __restrict__ counts) {
    int grp = blockIdx.x & 7;
    int nlo = grp * range;
    int nhi = nlo + range;
    int nblk = gridDim.x >> 3;
    int c = blockIdx.x >> 3;
    int stride = nblk * blockDim.x;
    for (int e = c * blockDim.x + threadIdx.x; e < E; e += stride) {
        int d = dst[e];
        if (d >= nlo && d < nhi) atomicAdd(&counts[d], 1);
    }
}

__global__ void scan_pass1(const int* __restrict__ counts, int n, int* __restrict__ blockSums) {
    __shared__ int sh[256];
    int base = blockIdx.x * 2048;
    int tid = threadIdx.x;
    int s = 0;
#pragma unroll
    for (int j = 0; j < 8; ++j) {
        int idx = base + tid * 8 + j;
        if (idx < n) s += counts[idx];
    }
    sh[tid] = s;
    __syncthreads();
    for (int off = 128; off > 0; off >>= 1) {
        if (tid < off) sh[tid] += sh[tid + off];
        __syncthreads();
    }
    if (tid == 0) blockSums[blockIdx.x] = sh[0];
}

__global__ void scan_pass2(const int* __restrict__ blockSums, int nb, int* __restrict__ blockOffs) {
    if (threadIdx.x == 0 && blockIdx.x == 0) {
        int run = 0;
        for (int i = 0; i < nb; ++i) { blockOffs[i] = run; run += blockSums[i]; }
    }
}

__global__ void scan_pass3(const int* __restrict__ counts, int n,
                           const int* __restrict__ blockOffs,
                           const float* __restrict__ x,
                           int* __restrict__ row_ptr, int* __restrict__ cursor,
                           float* __restrict__ dinv, float* __restrict__ rdinv,
                           _Float16* __restrict__ xs) {
    __shared__ int sh[256];
    int base = blockIdx.x * 2048;
    int tid = threadIdx.x;
    int cnt[8];
    int local = 0;
#pragma unroll
    for (int j = 0; j < 8; ++j) {
        int idx = base + tid * 8 + j;
        cnt[j] = (idx < n) ? counts[idx] : 0;
        local += cnt[j];
    }
    sh[tid] = local;
    __syncthreads();
    for (int off = 1; off < 256; off <<= 1) {
        int v = (tid >= off) ? sh[tid - off] : 0;
        __syncthreads();
        sh[tid] += v;
        __syncthreads();
    }
    int run = blockOffs[blockIdx.x] + sh[tid] - local;
#pragma unroll
    for (int j = 0; j < 8; ++j) {
        int idx = base + tid * 8 + j;
        if (idx < n) {
            row_ptr[idx] = run;
            cursor[idx] = run;
            float dv = rsqrtf((float)(cnt[j] + 1));
            dinv[idx] = dv;
            rdinv[idx] = sqrtf((float)(cnt[j] + 1));
#pragma unroll
            for (int t = 0; t < 8; ++t) xs[idx * 8 + t] = (_Float16)(dv * x[idx * 8 + t]);
            run += cnt[j];
            if (idx == n - 1) row_ptr[n] = run;
        }
    }
}

// XCD-range-filtered scatter (R9, kept): col_src/cursor writes stay XCD-local.
__global__ void scatter_kernel(const int* __restrict__ src, const int* __restrict__ dst,
                               int E, int range,
                               int* __restrict__ cursor, int* __restrict__ col_src) {
    int grp = blockIdx.x & 7;
    int nlo = grp * range;
    int nhi = nlo + range;
    int nblk = gridDim.x >> 3;
    int c = blockIdx.x >> 3;
    int stride = nblk * blockDim.x;
    for (int e = c * blockDim.x + threadIdx.x; e < E; e += stride) {
        int d = dst[e];
        if (d >= nlo && d < nhi) {
            int pos = atomicAdd(&cursor[d], 1);
            col_src[pos] = src[e];
        }
    }
}

// ---- weight precompute: Ccomb (fp16 split, B-frag order) + attn vectors ---

__global__ void ccomb_kernel(const float* __restrict__ Wg, const float* __restrict__ bg,
                             const float* __restrict__ wc1, const float* __restrict__ bc1,
                             const float* __restrict__ att_src, const float* __restrict__ att_dst,
                             _Float16* __restrict__ CcombP, float* __restrict__ bcomb,
                             float* __restrict__ wse, float* __restrict__ wde) {
    int bid = blockIdx.x;   // 0..256
    int j = threadIdx.x;    // 64 threads
    if (bid < 256) {
        int i = bid;        // k index (agg channel)
        float s = 0.f;
        for (int c = 0; c < 64; ++c)
            s += Wg[(i & 63) * 256 + (i >> 6) * 64 + c] * wc1[((i >> 6) * 64 + c) * 64 + j];
        _Float16 hi = (_Float16)s;
        _Float16 lo = (_Float16)(s - (float)hi);
        int kt = i >> 5, l = (((i >> 3) & 3) << 4) | (j & 15), e = i & 7, ct = j >> 4;
        CcombP[(ct * 8 + kt) * 512 + l * 8 + e] = hi;
        CcombP[(32 + ct * 8 + kt) * 512 + l * 8 + e] = lo;
    } else {
        float s = bc1[j];
        for (int i = 0; i < 256; ++i) s += bg[i] * wc1[i * 64 + j];
        bcomb[j] = s;
#pragma unroll
        for (int h = 0; h < 4; ++h) {
            float ss = 0.f, sd = 0.f;
            for (int c = 0; c < 64; ++c) {
                float w = Wg[j * 256 + h * 64 + c];
                ss += w * att_src[h * 64 + c];
                sd += w * att_dst[h * 64 + c];
            }
            wse[j * 4 + h] = ss;
            wde[j * 4 + h] = sd;
        }
    }
}

// ---- GCN layer 1: one edge per lane (16B half8 row) -----------------------

__global__ void gcn_layer1(const half8* __restrict__ xs8,
                           const float* __restrict__ W1, const float* __restrict__ b1,
                           const int* __restrict__ row_ptr, const int* __restrict__ col_src,
                           const float* __restrict__ dinv, int n,
                           _Float16* __restrict__ hs1) {
    int tid = threadIdx.x, lane = tid & 63, wid = tid >> 6;
    int node = blockIdx.x * 4 + wid;
    if (node >= n) return;
    int beg = row_ptr[node], end = row_ptr[node + 1];
    int deg = end - beg;
    float acc[8] = {0.f, 0.f, 0.f, 0.f, 0.f, 0.f, 0.f, 0.f};
    for (int base = 0; base < deg; base += 64) {
        int cs = col_src[min(beg + base + lane, end - 1)];
        half8 v = xs8[cs];
        if (base + lane < deg) {
#pragma unroll
            for (int c = 0; c < 8; ++c) acc[c] += (float)v[c];
        }
    }
#pragma unroll
    for (int c = 0; c < 8; ++c) acc[c] = red64(acc[c]);
    half8 sv = xs8[node];
    float di = dinv[node];
    float agg[8];
#pragma unroll
    for (int c = 0; c < 8; ++c) agg[c] = (acc[c] + (float)sv[c]) * di;
    float sum = b1[lane];
#pragma unroll
    for (int k = 0; k < 8; ++k) sum = fmaf(agg[k], W1[k * 64 + lane], sum);
    hs1[node * 64 + lane] = (_Float16)(di * fmaxf(sum, 0.f));
}

// ---- GCN layer 2/3: g=lane&7 edge slots, t=lane>>3 channel chunks ---------

template <bool LAST>
__global__ void gcn_layer64(const _Float16* __restrict__ hs_in,
                            const float* __restrict__ W, const float* __restrict__ b,
                            const int* __restrict__ row_ptr, const int* __restrict__ col_src,
                            const float* __restrict__ dinv, const float* __restrict__ rdinv,
                            const float* __restrict__ wse, const float* __restrict__ wde,
                            int n,
                            _Float16* __restrict__ hout,
                            float4* __restrict__ a_src4, float4* __restrict__ a_dst4) {
    __shared__ float agg_lds[4][64];
    int tid = threadIdx.x;
    int lane = tid & 63;
    int wid = tid >> 6;
    int t = lane >> 3, g = lane & 7;
    const half8* hs8 = (const half8*)hs_in;
    float wreg[64];
#pragma unroll
    for (int k = 0; k < 64; ++k) wreg[k] = W[k * 64 + lane];
    float bl = b[lane];
    float4 we, wd;
    if (LAST) {
        we = ((const float4*)wse)[lane];
        wd = ((const float4*)wde)[lane];
    }
    int nw = gridDim.x * 4;
    for (int node = blockIdx.x * 4 + wid; node < n; node += nw) {
        int beg = row_ptr[node], end = row_ptr[node + 1];
        int deg = end - beg;
        half8 sv = hs8[node * 8 + t];
        float ac[8];
#pragma unroll
        for (int c = 0; c < 8; ++c) ac[c] = (g == 0) ? (float)sv[c] : 0.f;
        for (int base = 0; base < deg; base += 64) {
            int cs = col_src[min(beg + base + lane, end - 1)];
            int lim = min(deg - base, 64);
            auto bodyF = [&](int eo8) {
                int s = __shfl(cs, eo8 + g);
                half8 v = hs8[s * 8 + t];
#pragma unroll
                for (int c = 0; c < 8; ++c) ac[c] += (float)v[c];
            };
            auto bodyG = [&](int eo8) {
                int eo = eo8 + g;
                int s = __shfl(cs, eo);
                half8 v = hs8[s * 8 + t];
                if (eo < lim) {
#pragma unroll
                    for (int c = 0; c < 8; ++c) ac[c] += (float)v[c];
                }
            };
            int eo8 = 0;
            for (; eo8 + 16 <= lim; eo8 += 16) { bodyF(eo8); bodyF(eo8 + 8); }
            if (eo8 < lim) {
                bodyG(eo8);
                eo8 += 8;
                if (eo8 < lim) bodyG(eo8);
            }
        }
        float di = dinv[node];
#pragma unroll
        for (int c = 0; c < 8; ++c) ac[c] = red8(ac[c]) * di;
        if (g == 0) {
            *(float4*)&agg_lds[wid][t * 8]     = make_float4(ac[0], ac[1], ac[2], ac[3]);
            *(float4*)&agg_lds[wid][t * 8 + 4] = make_float4(ac[4], ac[5], ac[6], ac[7]);
        }
        __asm__ volatile("s_waitcnt lgkmcnt(0)" ::: "memory");
        float sum = bl;
#pragma unroll
        for (int k4 = 0; k4 < 16; ++k4) {
            float4 a4 = *(const float4*)&agg_lds[wid][k4 * 4];
            sum = fmaf(a4.x, wreg[k4 * 4 + 0], sum);
            sum = fmaf(a4.y, wreg[k4 * 4 + 1], sum);
            sum = fmaf(a4.z, wreg[k4 * 4 + 2], sum);
            sum = fmaf(a4.w, wreg[k4 * 4 + 3], sum);
        }
        float hprev = rdinv[node] * (float)sv[g];
        float hv = hprev + fmaxf(sum, 0.f);
        if (!LAST) {
            hout[node * 64 + lane] = (_Float16)(di * hv);
        } else {
            hout[node * 64 + lane] = (_Float16)hv;
            float vs0 = red64(hv * we.x), vs1 = red64(hv * we.y);
            float vs2 = red64(hv * we.z), vs3 = red64(hv * we.w);
            float vd0 = red64(hv * wd.x), vd1 = red64(hv * wd.y);
            float vd2 = red64(hv * wd.z), vd3 = red64(hv * wd.w);
            if (lane == 0) {
                a_src4[node] = make_float4(vs0, vs1, vs2, vs3);
                a_dst4[node] = make_float4(vd0, vd1, vd2, vd3);
            }
        }
    }
}

// ---- GAT aggregate on matrix cores (no tr-reads) --------------------------
//
// Per node (1 wave): out[4h][64c] = W[4,K] x H[K,64], K-tiles of 32 slots
// (slot 0 = self). A-frag: wAT[m][slot] (m 0-3 hi heads, 4-7 lo heads),
// read as ds_read_b128: A[m=l&15][k=(l>>4)*8+e]. B-frag: Hs[32][72] halves,
// element (k,ch) at k*72 + (ch ^ ((k>>3)<<4)); 32x ds_read_u16 per lane:
// B[k=(l>>4)*8+e][n=l&15 (+ct*16)]. C: lane l<16 reg r = head r (hi) on
// rows 0-3, lo on rows 4-7 via lanes 16-31 -> combined with shfl_xor(16).

__global__ void gat_agg(const _Float16* __restrict__ h3,
                        const float4* __restrict__ a_src4, const float4* __restrict__ a_dst4,
                        const int* __restrict__ row_ptr, const int* __restrict__ col_src,
                        int n, _Float16* __restrict__ aggout) {
    __shared__ _Float16 HsAll[4][32 * 72];   // 4608B per wave, XOR-swizzled
    __shared__ _Float16 wATAll[4][16 * 40];  // 1280B per wave (rows 8..15 unused)
    int tid = threadIdx.x, lane = tid & 63, wid = tid >> 6;
    int node = blockIdx.x * 4 + wid;
    if (node >= n) return;
    _Float16* Hs = HsAll[wid];
    _Float16* wAT = wATAll[wid];

    int q = lane >> 4, m16 = lane & 15;
    float4 ad = a_dst4[node];
    int beg = row_ptr[node], end = row_ptr[node + 1];
    int deg = end - beg;
    int nslots = deg + 1;

    f32x4 acc0 = {0.f,0.f,0.f,0.f}, acc1 = {0.f,0.f,0.f,0.f};
    f32x4 acc2 = {0.f,0.f,0.f,0.f}, acc3 = {0.f,0.f,0.f,0.f};
    float dh0 = 0.f, dh1 = 0.f, dh2 = 0.f, dh3 = 0.f;
    float m0 = 0.f, m1 = 0.f, m2 = 0.f, m3 = 0.f;
    int c0 = (lane & 7) * 8;

    for (int base = 0; base < nslots; base += 32) {
        int sl = base + (lane & 31);
        int eidx = max(min(beg + sl - 1, end - 1), 0);
        int cs = (sl == 0) ? node : col_src[eidx];
        float4 as = a_src4[cs];
        float vm = (sl < nslots && lane < 32) ? 1.f : 0.f;
        float l0 = leaky02(as.x + ad.x);
        float l1 = leaky02(as.y + ad.y);
        float l2 = leaky02(as.z + ad.z);
        float l3 = leaky02(as.w + ad.w);
        if (base == 0) {   // per-head shift from tile 0 (includes self)
            m0 = red64max(vm > 0.f ? l0 : -1e30f);
            m1 = red64max(vm > 0.f ? l1 : -1e30f);
            m2 = red64max(vm > 0.f ? l2 : -1e30f);
            m3 = red64max(vm > 0.f ? l3 : -1e30f);
        }
        // clamp keeps exp <= e^10 (fp16-safe); applied to numerator AND dh.
        float w0 = vm * __expf(fminf(l0 - m0, 10.f));
        float w1 = vm * __expf(fminf(l1 - m1, 10.f));
        float w2 = vm * __expf(fminf(l2 - m2, 10.f));
        float w3 = vm * __expf(fminf(l3 - m3, 10.f));
        dh0 += w0; dh1 += w1; dh2 += w2; dh3 += w3;
        if (lane < 32) {
            int s32 = lane & 31;
            _Float16 h0 = (_Float16)w0, h1 = (_Float16)w1;
            _Float16 h2 = (_Float16)w2, h3v = (_Float16)w3;
            wAT[0 * 40 + s32] = h0;
            wAT[1 * 40 + s32] = h1;
            wAT[2 * 40 + s32] = h2;
            wAT[3 * 40 + s32] = h3v;
            wAT[4 * 40 + s32] = (_Float16)(w0 - (float)h0);
            wAT[5 * 40 + s32] = (_Float16)(w1 - (float)h1);
            wAT[6 * 40 + s32] = (_Float16)(w2 - (float)h2);
            wAT[7 * 40 + s32] = (_Float16)(w3 - (float)h3v);
        }
        // H gather -> swizzled Hs: elem (r, c) at r*72 + (c ^ ((r>>3)<<4))
#pragma unroll
        for (int i = 0; i < 4; ++i) {
            int r = i * 8 + (lane >> 3);         // r>>3 == i
            int s = __shfl(cs, r);
            half8 hv = *(const half8*)(h3 + (size_t)s * 64 + c0);
            *(half8*)(Hs + r * 72 + (c0 ^ (i << 4))) = hv;
        }
        __asm__ volatile("s_waitcnt lgkmcnt(0)" ::: "memory");
        // A-frag: row m16, slots q*8..q*8+7 (rows 8..15 feed unread C rows)
        f16x8 A = *(const f16x8*)(wAT + m16 * 40 + q * 8);
        // B-frags: 8 scalar reads each; per-lane swizzle const (q<<4)
        f16x8 B0, B1, B2, B3;
#pragma unroll
        for (int e = 0; e < 8; ++e) {
            int k = q * 8 + e;
            int rb = k * 72;
            B0[e] = Hs[rb + ((0 * 16 + m16) ^ (q << 4))];
            B1[e] = Hs[rb + ((1 * 16 + m16) ^ (q << 4))];
            B2[e] = Hs[rb + ((2 * 16 + m16) ^ (q << 4))];
            B3[e] = Hs[rb + ((3 * 16 + m16) ^ (q << 4))];
        }
        acc0 = __builtin_amdgcn_mfma_f32_16x16x32_f16(A, B0, acc0, 0, 0, 0);
        acc1 = __builtin_amdgcn_mfma_f32_16x16x32_f16(A, B1, acc1, 0, 0, 0);
        acc2 = __builtin_amdgcn_mfma_f32_16x16x32_f16(A, B2, acc2, 0, 0, 0);
        acc3 = __builtin_amdgcn_mfma_f32_16x16x32_f16(A, B3, acc3, 0, 0, 0);
        __asm__ volatile("s_waitcnt lgkmcnt(0)" ::: "memory");  // done with Hs/wAT before next tile's writes
    }

    dh0 = red64(dh0); dh1 = red64(dh1); dh2 = red64(dh2); dh3 = red64(dh3);
    float rd[4];
    rd[0] = 1.f / (dh0 + 1e-16f);
    rd[1] = 1.f / (dh1 + 1e-16f);
    rd[2] = 1.f / (dh2 + 1e-16f);
    rd[3] = 1.f / (dh3 + 1e-16f);
    // combine hi (rows 0-3, lanes 0-15) + lo (rows 4-7, lanes 16-31)
    float tot[4][4];   // [ct][r]
#pragma unroll
    for (int r = 0; r < 4; ++r) {
        tot[0][r] = acc0[r] + __shfl_xor(acc0[r], 16);
        tot[1][r] = acc1[r] + __shfl_xor(acc1[r], 16);
        tot[2][r] = acc2[r] + __shfl_xor(acc2[r], 16);
        tot[3][r] = acc3[r] + __shfl_xor(acc3[r], 16);
    }
    if (lane < 16) {
        size_t ob = (size_t)node * 256 + lane;
#pragma unroll
        for (int r = 0; r < 4; ++r) {
#pragma unroll
            for (int ct = 0; ct < 4; ++ct)
                aggout[ob + r * 64 + ct * 16] = (_Float16)(tot[ct][r] * rd[r]);
        }
    }
}

// ---- MLP on matrix cores: Z = relu(AGG @ C) then 64->3 + log_softmax ------

__global__ __launch_bounds__(256) void mlp_mfma(
        const _Float16* __restrict__ agg,
        const _Float16* __restrict__ CP,
        const float* __restrict__ bcomb,
        const float* __restrict__ wc2, const float* __restrict__ bc2,
        int n, float* __restrict__ out) {
    __shared__ float part[4][16][3];
    int tid = threadIdx.x;
    int lane = tid & 63;
    int w = __builtin_amdgcn_readfirstlane(tid >> 6);   // ct slice
    int c16 = lane & 15, hi = lane >> 4;

    f16x8 bh[8], blo[8];
#pragma unroll
    for (int kt = 0; kt < 8; ++kt) {
        bh[kt]  = *(const f16x8*)(CP + (size_t)(w * 8 + kt) * 512 + lane * 8);
        blo[kt] = *(const f16x8*)(CP + (size_t)(32 + w * 8 + kt) * 512 + lane * 8);
    }
    int col = w * 16 + c16;
    float bc  = bcomb[col];
    float w20 = wc2[col * 3 + 0], w21 = wc2[col * 3 + 1], w22 = wc2[col * 3 + 2];
    float bb0 = bc2[0], bb1 = bc2[1], bb2 = bc2[2];

    int ntiles = (n + 15) >> 4;
    for (int tile = blockIdx.x; tile < ntiles; tile += gridDim.x) {
        int rowb = tile * 16;
        int row = min(rowb + c16, n - 1);
        const _Float16* ap = agg + (size_t)row * 256 + hi * 8;
        f16x8 a[8];
#pragma unroll
        for (int kt = 0; kt < 8; ++kt) a[kt] = *(const f16x8*)(ap + kt * 32);
        f32x4 acc = {0.f, 0.f, 0.f, 0.f};
#pragma unroll
        for (int kt = 0; kt < 8; ++kt) {
            acc = __builtin_amdgcn_mfma_f32_16x16x32_f16(a[kt], bh[kt],  acc, 0, 0, 0);
            acc = __builtin_amdgcn_mfma_f32_16x16x32_f16(a[kt], blo[kt], acc, 0, 0, 0);
        }
        float pr[4][3];
#pragma unroll
        for (int r = 0; r < 4; ++r) {
            float z = fmaxf(acc[r] + bc, 0.f);
            pr[r][0] = red16(z * w20);
            pr[r][1] = red16(z * w21);
            pr[r][2] = red16(z * w22);
        }
        if (c16 == 0) {
#pragma unroll
            for (int r = 0; r < 4; ++r) {
                part[w][hi * 4 + r][0] = pr[r][0];
                part[w][hi * 4 + r][1] = pr[r][1];
                part[w][hi * 4 + r][2] = pr[r][2];
            }
        }
        __syncthreads();
        if (tid < 16) {
            int node = rowb + tid;
            if (node < n) {
                float e0 = part[0][tid][0] + part[1][tid][0] + part[2][tid][0] + part[3][tid][0] + bb0;
                float e1 = part[0][tid][1] + part[1][tid][1] + part[2][tid][1] + part[3][tid][1] + bb1;
                float e2 = part[0][tid][2] + part[1][tid][2] + part[2][tid][2] + part[3][tid][2] + bb2;
                float mx = fmaxf(e0, fmaxf(e1, e2));
                float lse = mx + logf(expf(e0 - mx) + expf(e1 - mx) + expf(e2 - mx));
                out[(size_t)node * 3 + 0] = e0 - lse;
                out[(size_t)node * 3 + 1] = e1 - lse;
                out[(size_t)node * 3 + 2] = e2 - lse;
            }
        }
        __syncthreads();
    }
}

// ---------------------------------------------------------------------------

extern "C" void kernel_launch(void* const* d_in, const int* in_sizes, int n_in,
                              void* d_out, int out_size, void* d_ws, size_t ws_size,
                              hipStream_t stream) {
    const float* x       = (const float*)d_in[0];
    const int*   ei      = (const int*)d_in[1];
    const float* w1      = (const float*)d_in[2];
    const float* b1      = (const float*)d_in[3];
    const float* w2      = (const float*)d_in[4];
    const float* b2      = (const float*)d_in[5];
    const float* w3      = (const float*)d_in[6];
    const float* b3      = (const float*)d_in[7];
    const float* wg      = (const float*)d_in[8];
    const float* bg      = (const float*)d_in[9];
    const float* att_s   = (const float*)d_in[10];
    const float* att_d   = (const float*)d_in[11];
    const float* wc1     = (const float*)d_in[12];
    const float* bc1     = (const float*)d_in[13];
    const float* wc2     = (const float*)d_in[14];
    const float* bc2     = (const float*)d_in[15];
    float* out = (float*)d_out;

    const int N = in_sizes[0] / 8;
    const int E = in_sizes[1] / 2;
    const int* srcv = ei;
    const int* dstv = ei + E;

    char* ws = (char*)d_ws;
    size_t off = 0;
    auto alloc = [&](size_t bytes) -> char* {
        char* p = ws + off;
        off += (bytes + 255) & ~(size_t)255;
        return p;
    };
    int*      counts    = (int*)alloc((size_t)N * 4);
    int*      row_ptr   = (int*)alloc((size_t)(N + 1) * 4);
    int*      cursor    = (int*)alloc((size_t)N * 4);
    int*      col_src   = (int*)alloc((size_t)E * 4);
    int*      blockSums = (int*)alloc(4096 * 4);
    int*      blockOffs = (int*)alloc(4096 * 4);
    float*    dinv      = (float*)alloc((size_t)N * 4);
    float*    rdinv     = (float*)alloc((size_t)N * 4);
    _Float16* xs        = (_Float16*)alloc((size_t)N * 8 * 2);
    float*    a_src     = (float*)alloc((size_t)N * 16);
    float*    a_dst     = (float*)alloc((size_t)N * 16);
    float*    wse       = (float*)alloc(256 * 4);
    float*    wde       = (float*)alloc(256 * 4);
    _Float16* CcombP    = (_Float16*)alloc(64 * 1024);           // fp16 hi+lo B-frags
    float*    bcomb     = (float*)alloc(64 * 4);
    _Float16* bufA      = (_Float16*)alloc((size_t)N * 64 * 2);  // hs1, later h3
    _Float16* bufB      = (_Float16*)alloc((size_t)N * 64 * 2);  // hs2
    _Float16* aggbuf    = (_Float16*)alloc((size_t)N * 256 * 2); // 51.2MB fp16
    _Float16* hs1 = bufA;
    _Float16* hs2 = bufB;
    _Float16* h3  = bufA;   // hs1 dead once layer3 runs
    (void)ws_size; (void)n_in; (void)out_size;

    hipMemsetAsync(counts, 0, (size_t)N * 4, stream);

    const int TPB = 256;
    int range = (N + 7) / 8;
    count_kernel<<<1024, TPB, 0, stream>>>(dstv, E, range, counts);

    int NB = (N + 2047) / 2048;
    scan_pass1<<<NB, TPB, 0, stream>>>(counts, N, blockSums);
    scan_pass2<<<1, 64, 0, stream>>>(blockSums, NB, blockOffs);
    scan_pass3<<<NB, TPB, 0, stream>>>(counts, N, blockOffs, x,
                                       row_ptr, cursor, dinv, rdinv, xs);
    scatter_kernel<<<2048, TPB, 0, stream>>>(srcv, dstv, E, range, cursor, col_src);

    ccomb_kernel<<<257, 64, 0, stream>>>(wg, bg, wc1, bc1, att_s, att_d,
                                         CcombP, bcomb, wse, wde);

    int gridN = (N + 3) / 4;
    gcn_layer1<<<gridN, TPB, 0, stream>>>((const half8*)xs, w1, b1, row_ptr, col_src,
                                          dinv, N, hs1);
    const int G64 = 2048;
    gcn_layer64<false><<<G64, TPB, 0, stream>>>(hs1, w2, b2, row_ptr, col_src,
                                                dinv, rdinv, wse, wde, N, hs2,
                                                nullptr, nullptr);
    gcn_layer64<true><<<G64, TPB, 0, stream>>>(hs2, w3, b3, row_ptr, col_src,
                                               dinv, rdinv, wse, wde, N, h3,
                                               (float4*)a_src, (float4*)a_dst);

    gat_agg<<<gridN, TPB, 0, stream>>>(h3, (const float4*)a_src, (const float4*)a_dst,
                                       row_ptr, col_src, N, aggbuf);
    mlp_mfma<<<2048, TPB, 0, stream>>>(aggbuf, CcombP, bcomb, wc2, bc2, N, out);
}

// Round 6
// 551.468 us; speedup vs baseline: 1.1713x; 1.0005x over previous
//
#include <hip/hip_runtime.h>
#include <math.h>

// ---------------------------------------------------------------------------
// SpatialGNN: 3x GCN (residual) + 4-head GAT + MLP + log_softmax
// N=100000, E=1600000, IN=8, HID=64, HEADS=4, OUT=3
//
// R16 = R14 (last passing, 551.7us) + surgical gat_agg codegen fixes:
//  - __launch_bounds__(256, 4): VGPR cap 128 (was compiler-chosen 48 ->
//    ~800 VALU inst/node from rematerialized addressing; occupancy measured
//    49% =~ 4 waves/SIMD, so 128 VGPRs cost nothing).
//  - B-read base addresses (lane-constant: Hs + ((ct*16+m16)^(q<<4))) and
//    A-frag base hoisted out of the K-loop; inner reads use compile-time
//    e*72 element offsets -> ds_read_u16 with immediate offsets, no
//    per-element VALU.
//  - NO tr-reads (two failed probes: R13 absmax 0.109, R15 absmax 5567 —
//    ds_read_b64_tr_b16 per-lane semantics don't match the documented
//    model; banned for this session).
//  - all numerics/sync byte-identical to R14.
// ---------------------------------------------------------------------------

typedef _Float16 half8 __attribute__((ext_vector_type(8)));
typedef _Float16 f16x8 __attribute__((ext_vector_type(8)));
typedef float f32x4 __attribute__((ext_vector_type(4)));

__device__ __forceinline__ float leaky02(float v) { return v > 0.f ? v : 0.2f * v; }

// ---- cross-lane reduction helpers (DPP/swizzle; minimize DS-pipe ops) -----

template <int CTRL>
__device__ __forceinline__ float dpp_add(float v) {
    int iv = __builtin_bit_cast(int, v);
    int r = __builtin_amdgcn_update_dpp(iv, iv, CTRL, 0xF, 0xF, false);
    return v + __builtin_bit_cast(float, r);
}
template <int OFF>
__device__ __forceinline__ float swz_add(float v) {
    int r = __builtin_amdgcn_ds_swizzle(__builtin_bit_cast(int, v), OFF);
    return v + __builtin_bit_cast(float, r);
}
template <int CTRL>
__device__ __forceinline__ float dpp_max(float v) {
    int iv = __builtin_bit_cast(int, v);
    int r = __builtin_amdgcn_update_dpp(iv, iv, CTRL, 0xF, 0xF, false);
    return fmaxf(v, __builtin_bit_cast(float, r));
}
template <int OFF>
__device__ __forceinline__ float swz_max(float v) {
    int r = __builtin_amdgcn_ds_swizzle(__builtin_bit_cast(int, v), OFF);
    return fmaxf(v, __builtin_bit_cast(float, r));
}
__device__ __forceinline__ float red8(float v) {
    v = dpp_add<0xB1>(v);     // xor1
    v = dpp_add<0x4E>(v);     // xor2
    v = swz_add<0x101F>(v);   // xor4
    return v;
}
__device__ __forceinline__ float red16(float v) {
    v = dpp_add<0xB1>(v);
    v = dpp_add<0x4E>(v);
    v = swz_add<0x101F>(v);
    v = dpp_add<0x128>(v);    // row_ror:8 -> completes 16-lane sum
    return v;
}
__device__ __forceinline__ float red64(float v) {
    v = dpp_add<0xB1>(v);
    v = dpp_add<0x4E>(v);
    v = swz_add<0x101F>(v);
    v = dpp_add<0x128>(v);    // xor8: row_ror:8
    v = swz_add<0x401F>(v);   // xor16
    v = v + __shfl_xor(v, 32);
    return v;
}
__device__ __forceinline__ float red64max(float v) {
    v = dpp_max<0xB1>(v);
    v = dpp_max<0x4E>(v);
    v = swz_max<0x101F>(v);
    v = dpp_max<0x128>(v);
    v = swz_max<0x401F>(v);
    v = fmaxf(v, __shfl_xor(v, 32));
    return v;
}

// ---- CSR build ------------------------------------------------------------

// XCD-range-filtered count: group blockIdx&7 counts only its dst range.
__global__ void count_kernel(const int* __restrict__ dst, int E, int range,
                             int* __restrict__ counts) {
    int grp = blockIdx.x & 7;
    int nlo = grp * range;
    int nhi = nlo + range;
    int nblk = gridDim.x >> 3;
    int c = blockIdx.x >> 3;
    int stride = nblk * blockDim.x;
    for (int e = c * blockDim.x + threadIdx.x; e < E; e += stride) {
        int d = dst[e];
        if (d >= nlo && d < nhi) atomicAdd(&counts[d], 1);
    }
}

__global__ void scan_pass1(const int* __restrict__ counts, int n, int* __restrict__ blockSums) {
    __shared__ int sh[256];
    int base = blockIdx.x * 2048;
    int tid = threadIdx.x;
    int s = 0;
#pragma unroll
    for (int j = 0; j < 8; ++j) {
        int idx = base + tid * 8 + j;
        if (idx < n) s += counts[idx];
    }
    sh[tid] = s;
    __syncthreads();
    for (int off = 128; off > 0; off >>= 1) {
        if (tid < off) sh[tid] += sh[tid + off];
        __syncthreads();
    }
    if (tid == 0) blockSums[blockIdx.x] = sh[0];
}

__global__ void scan_pass2(const int* __restrict__ blockSums, int nb, int* __restrict__ blockOffs) {
    if (threadIdx.x == 0 && blockIdx.x == 0) {
        int run = 0;
        for (int i = 0; i < nb; ++i) { blockOffs[i] = run; run += blockSums[i]; }
    }
}

__global__ void scan_pass3(const int* __restrict__ counts, int n,
                           const int* __restrict__ blockOffs,
                           const float* __restrict__ x,
                           int* __restrict__ row_ptr, int* __restrict__ cursor,
                           float* __restrict__ dinv, float* __restrict__ rdinv,
                           _Float16* __restrict__ xs) {
    __shared__ int sh[256];
    int base = blockIdx.x * 2048;
    int tid = threadIdx.x;
    int cnt[8];
    int local = 0;
#pragma unroll
    for (int j = 0; j < 8; ++j) {
        int idx = base + tid * 8 + j;
        cnt[j] = (idx < n) ? counts[idx] : 0;
        local += cnt[j];
    }
    sh[tid] = local;
    __syncthreads();
    for (int off = 1; off < 256; off <<= 1) {
        int v = (tid >= off) ? sh[tid - off] : 0;
        __syncthreads();
        sh[tid] += v;
        __syncthreads();
    }
    int run = blockOffs[blockIdx.x] + sh[tid] - local;
#pragma unroll
    for (int j = 0; j < 8; ++j) {
        int idx = base + tid * 8 + j;
        if (idx < n) {
            row_ptr[idx] = run;
            cursor[idx] = run;
            float dv = rsqrtf((float)(cnt[j] + 1));
            dinv[idx] = dv;
            rdinv[idx] = sqrtf((float)(cnt[j] + 1));
#pragma unroll
            for (int t = 0; t < 8; ++t) xs[idx * 8 + t] = (_Float16)(dv * x[idx * 8 + t]);
            run += cnt[j];
            if (idx == n - 1) row_ptr[n] = run;
        }
    }
}

// XCD-range-filtered scatter (R9, kept): col_src/cursor writes stay XCD-local.
__global__ void scatter_kernel(const int* __restrict__ src, const int* __restrict__ dst,
                               int E, int range,
                               int* __restrict__ cursor, int* __restrict__ col_src) {
    int grp = blockIdx.x & 7;
    int nlo = grp * range;
    int nhi = nlo + range;
    int nblk = gridDim.x >> 3;
    int c = blockIdx.x >> 3;
    int stride = nblk * blockDim.x;
    for (int e = c * blockDim.x + threadIdx.x; e < E; e += stride) {
        int d = dst[e];
        if (d >= nlo && d < nhi) {
            int pos = atomicAdd(&cursor[d], 1);
            col_src[pos] = src[e];
        }
    }
}

// ---- weight precompute: Ccomb (fp16 split, B-frag order) + attn vectors ---

__global__ void ccomb_kernel(const float* __restrict__ Wg, const float* __restrict__ bg,
                             const float* __restrict__ wc1, const float* __restrict__ bc1,
                             const float* __restrict__ att_src, const float* __restrict__ att_dst,
                             _Float16* __restrict__ CcombP, float* __restrict__ bcomb,
                             float* __restrict__ wse, float* __restrict__ wde) {
    int bid = blockIdx.x;   // 0..256
    int j = threadIdx.x;    // 64 threads
    if (bid < 256) {
        int i = bid;        // k index (agg channel)
        float s = 0.f;
        for (int c = 0; c < 64; ++c)
            s += Wg[(i & 63) * 256 + (i >> 6) * 64 + c] * wc1[((i >> 6) * 64 + c) * 64 + j];
        _Float16 hi = (_Float16)s;
        _Float16 lo = (_Float16)(s - (float)hi);
        int kt = i >> 5, l = (((i >> 3) & 3) << 4) | (j & 15), e = i & 7, ct = j >> 4;
        CcombP[(ct * 8 + kt) * 512 + l * 8 + e] = hi;
        CcombP[(32 + ct * 8 + kt) * 512 + l * 8 + e] = lo;
    } else {
        float s = bc1[j];
        for (int i = 0; i < 256; ++i) s += bg[i] * wc1[i * 64 + j];
        bcomb[j] = s;
#pragma unroll
        for (int h = 0; h < 4; ++h) {
            float ss = 0.f, sd = 0.f;
            for (int c = 0; c < 64; ++c) {
                float w = Wg[j * 256 + h * 64 + c];
                ss += w * att_src[h * 64 + c];
                sd += w * att_dst[h * 64 + c];
            }
            wse[j * 4 + h] = ss;
            wde[j * 4 + h] = sd;
        }
    }
}

// ---- GCN layer 1: one edge per lane (16B half8 row) -----------------------

__global__ void gcn_layer1(const half8* __restrict__ xs8,
                           const float* __restrict__ W1, const float* __restrict__ b1,
                           const int* __restrict__ row_ptr, const int* __restrict__ col_src,
                           const float* __restrict__ dinv, int n,
                           _Float16* __restrict__ hs1) {
    int tid = threadIdx.x, lane = tid & 63, wid = tid >> 6;
    int node = blockIdx.x * 4 + wid;
    if (node >= n) return;
    int beg = row_ptr[node], end = row_ptr[node + 1];
    int deg = end - beg;
    float acc[8] = {0.f, 0.f, 0.f, 0.f, 0.f, 0.f, 0.f, 0.f};
    for (int base = 0; base < deg; base += 64) {
        int cs = col_src[min(beg + base + lane, end - 1)];
        half8 v = xs8[cs];
        if (base + lane < deg) {
#pragma unroll
            for (int c = 0; c < 8; ++c) acc[c] += (float)v[c];
        }
    }
#pragma unroll
    for (int c = 0; c < 8; ++c) acc[c] = red64(acc[c]);
    half8 sv = xs8[node];
    float di = dinv[node];
    float agg[8];
#pragma unroll
    for (int c = 0; c < 8; ++c) agg[c] = (acc[c] + (float)sv[c]) * di;
    float sum = b1[lane];
#pragma unroll
    for (int k = 0; k < 8; ++k) sum = fmaf(agg[k], W1[k * 64 + lane], sum);
    hs1[node * 64 + lane] = (_Float16)(di * fmaxf(sum, 0.f));
}

// ---- GCN layer 2/3: g=lane&7 edge slots, t=lane>>3 channel chunks ---------

template <bool LAST>
__global__ void gcn_layer64(const _Float16* __restrict__ hs_in,
                            const float* __restrict__ W, const float* __restrict__ b,
                            const int* __restrict__ row_ptr, const int* __restrict__ col_src,
                            const float* __restrict__ dinv, const float* __restrict__ rdinv,
                            const float* __restrict__ wse, const float* __restrict__ wde,
                            int n,
                            _Float16* __restrict__ hout,
                            float4* __restrict__ a_src4, float4* __restrict__ a_dst4) {
    __shared__ float agg_lds[4][64];
    int tid = threadIdx.x;
    int lane = tid & 63;
    int wid = tid >> 6;
    int t = lane >> 3, g = lane & 7;
    const half8* hs8 = (const half8*)hs_in;
    float wreg[64];
#pragma unroll
    for (int k = 0; k < 64; ++k) wreg[k] = W[k * 64 + lane];
    float bl = b[lane];
    float4 we, wd;
    if (LAST) {
        we = ((const float4*)wse)[lane];
        wd = ((const float4*)wde)[lane];
    }
    int nw = gridDim.x * 4;
    for (int node = blockIdx.x * 4 + wid; node < n; node += nw) {
        int beg = row_ptr[node], end = row_ptr[node + 1];
        int deg = end - beg;
        half8 sv = hs8[node * 8 + t];
        float ac[8];
#pragma unroll
        for (int c = 0; c < 8; ++c) ac[c] = (g == 0) ? (float)sv[c] : 0.f;
        for (int base = 0; base < deg; base += 64) {
            int cs = col_src[min(beg + base + lane, end - 1)];
            int lim = min(deg - base, 64);
            auto bodyF = [&](int eo8) {
                int s = __shfl(cs, eo8 + g);
                half8 v = hs8[s * 8 + t];
#pragma unroll
                for (int c = 0; c < 8; ++c) ac[c] += (float)v[c];
            };
            auto bodyG = [&](int eo8) {
                int eo = eo8 + g;
                int s = __shfl(cs, eo);
                half8 v = hs8[s * 8 + t];
                if (eo < lim) {
#pragma unroll
                    for (int c = 0; c < 8; ++c) ac[c] += (float)v[c];
                }
            };
            int eo8 = 0;
            for (; eo8 + 16 <= lim; eo8 += 16) { bodyF(eo8); bodyF(eo8 + 8); }
            if (eo8 < lim) {
                bodyG(eo8);
                eo8 += 8;
                if (eo8 < lim) bodyG(eo8);
            }
        }
        float di = dinv[node];
#pragma unroll
        for (int c = 0; c < 8; ++c) ac[c] = red8(ac[c]) * di;
        if (g == 0) {
            *(float4*)&agg_lds[wid][t * 8]     = make_float4(ac[0], ac[1], ac[2], ac[3]);
            *(float4*)&agg_lds[wid][t * 8 + 4] = make_float4(ac[4], ac[5], ac[6], ac[7]);
        }
        __asm__ volatile("s_waitcnt lgkmcnt(0)" ::: "memory");
        float sum = bl;
#pragma unroll
        for (int k4 = 0; k4 < 16; ++k4) {
            float4 a4 = *(const float4*)&agg_lds[wid][k4 * 4];
            sum = fmaf(a4.x, wreg[k4 * 4 + 0], sum);
            sum = fmaf(a4.y, wreg[k4 * 4 + 1], sum);
            sum = fmaf(a4.z, wreg[k4 * 4 + 2], sum);
            sum = fmaf(a4.w, wreg[k4 * 4 + 3], sum);
        }
        float hprev = rdinv[node] * (float)sv[g];
        float hv = hprev + fmaxf(sum, 0.f);
        if (!LAST) {
            hout[node * 64 + lane] = (_Float16)(di * hv);
        } else {
            hout[node * 64 + lane] = (_Float16)hv;
            float vs0 = red64(hv * we.x), vs1 = red64(hv * we.y);
            float vs2 = red64(hv * we.z), vs3 = red64(hv * we.w);
            float vd0 = red64(hv * wd.x), vd1 = red64(hv * wd.y);
            float vd2 = red64(hv * wd.z), vd3 = red64(hv * wd.w);
            if (lane == 0) {
                a_src4[node] = make_float4(vs0, vs1, vs2, vs3);
                a_dst4[node] = make_float4(vd0, vd1, vd2, vd3);
            }
        }
    }
}

// ---- GAT aggregate on matrix cores (no tr-reads, R14 structure) -----------
//
// Per node (1 wave): out[4h][64c] = W[4,K] x H[K,64], K-tiles of 32 slots
// (slot 0 = self). A-frag: wAT[m][slot] (m 0-3 hi heads, 4-7 lo heads),
// read as one ds_read_b128: A[m=l&15][k=(l>>4)*8+e]. B-frag: Hs[32][72]
// halves, element (k,ch) at k*72 + (ch ^ ((k>>3)<<4)); 32x ds_read_u16 per
// lane from 4 HOISTED lane-constant bases + compile-time e*72 offsets.
// C rows 0-3 = hi, 4-7 = lo -> combined with shfl_xor(16).

__global__ __launch_bounds__(256, 4) void gat_agg(
        const _Float16* __restrict__ h3,
        const float4* __restrict__ a_src4, const float4* __restrict__ a_dst4,
        const int* __restrict__ row_ptr, const int* __restrict__ col_src,
        int n, _Float16* __restrict__ aggout) {
    __shared__ _Float16 HsAll[4][32 * 72];   // 4608B per wave, XOR-swizzled
    __shared__ _Float16 wATAll[4][16 * 40];  // 1280B per wave (rows 8..15 unused)
    int tid = threadIdx.x, lane = tid & 63, wid = tid >> 6;
    int node = blockIdx.x * 4 + wid;
    if (node >= n) return;
    _Float16* Hs = HsAll[wid];
    _Float16* wAT = wATAll[wid];

    int q = lane >> 4, m16 = lane & 15;
    float4 ad = a_dst4[node];
    int beg = row_ptr[node], end = row_ptr[node + 1];
    int deg = end - beg;
    int nslots = deg + 1;

    // lane-constant fragment addresses, hoisted out of the K-loop
    int swz = q << 4;
    const _Float16* Bb0 = Hs + (size_t)q * 8 * 72 + ((0 * 16 + m16) ^ swz);
    const _Float16* Bb1 = Hs + (size_t)q * 8 * 72 + ((1 * 16 + m16) ^ swz);
    const _Float16* Bb2 = Hs + (size_t)q * 8 * 72 + ((2 * 16 + m16) ^ swz);
    const _Float16* Bb3 = Hs + (size_t)q * 8 * 72 + ((3 * 16 + m16) ^ swz);
    const f16x8* Ab = (const f16x8*)(wAT + m16 * 40 + q * 8);
    int c0 = (lane & 7) * 8;

    f32x4 acc0 = {0.f,0.f,0.f,0.f}, acc1 = {0.f,0.f,0.f,0.f};
    f32x4 acc2 = {0.f,0.f,0.f,0.f}, acc3 = {0.f,0.f,0.f,0.f};
    float dh0 = 0.f, dh1 = 0.f, dh2 = 0.f, dh3 = 0.f;
    float m0 = 0.f, m1 = 0.f, m2 = 0.f, m3 = 0.f;

    for (int base = 0; base < nslots; base += 32) {
        int sl = base + (lane & 31);
        int eidx = max(min(beg + sl - 1, end - 1), 0);
        int cs = (sl == 0) ? node : col_src[eidx];
        float4 as = a_src4[cs];
        float vm = (sl < nslots && lane < 32) ? 1.f : 0.f;
        float l0 = leaky02(as.x + ad.x);
        float l1 = leaky02(as.y + ad.y);
        float l2 = leaky02(as.z + ad.z);
        float l3 = leaky02(as.w + ad.w);
        if (base == 0) {   // per-head shift from tile 0 (includes self)
            m0 = red64max(vm > 0.f ? l0 : -1e30f);
            m1 = red64max(vm > 0.f ? l1 : -1e30f);
            m2 = red64max(vm > 0.f ? l2 : -1e30f);
            m3 = red64max(vm > 0.f ? l3 : -1e30f);
        }
        // clamp keeps exp <= e^10 (fp16-safe); applied to numerator AND dh.
        float w0 = vm * __expf(fminf(l0 - m0, 10.f));
        float w1 = vm * __expf(fminf(l1 - m1, 10.f));
        float w2 = vm * __expf(fminf(l2 - m2, 10.f));
        float w3 = vm * __expf(fminf(l3 - m3, 10.f));
        dh0 += w0; dh1 += w1; dh2 += w2; dh3 += w3;
        if (lane < 32) {
            int s32 = lane & 31;
            _Float16 h0 = (_Float16)w0, h1 = (_Float16)w1;
            _Float16 h2 = (_Float16)w2, h3v = (_Float16)w3;
            wAT[0 * 40 + s32] = h0;
            wAT[1 * 40 + s32] = h1;
            wAT[2 * 40 + s32] = h2;
            wAT[3 * 40 + s32] = h3v;
            wAT[4 * 40 + s32] = (_Float16)(w0 - (float)h0);
            wAT[5 * 40 + s32] = (_Float16)(w1 - (float)h1);
            wAT[6 * 40 + s32] = (_Float16)(w2 - (float)h2);
            wAT[7 * 40 + s32] = (_Float16)(w3 - (float)h3v);
        }
        // H gather -> swizzled Hs: elem (r, c) at r*72 + (c ^ ((r>>3)<<4))
#pragma unroll
        for (int i = 0; i < 4; ++i) {
            int r = i * 8 + (lane >> 3);         // r>>3 == i
            int s = __shfl(cs, r);
            half8 hv = *(const half8*)(h3 + (size_t)s * 64 + c0);
            *(half8*)(Hs + r * 72 + (c0 ^ (i << 4))) = hv;
        }
        __asm__ volatile("s_waitcnt lgkmcnt(0)" ::: "memory");
        // A-frag: row m16, slots q*8..q*8+7 (rows 8..15 feed unread C rows)
        f16x8 A = *Ab;
        // B-frags: 8 reads each from hoisted bases, compile-time offsets
        f16x8 B0, B1, B2, B3;
#pragma unroll
        for (int e = 0; e < 8; ++e) {
            B0[e] = Bb0[e * 72];
            B1[e] = Bb1[e * 72];
            B2[e] = Bb2[e * 72];
            B3[e] = Bb3[e * 72];
        }
        acc0 = __builtin_amdgcn_mfma_f32_16x16x32_f16(A, B0, acc0, 0, 0, 0);
        acc1 = __builtin_amdgcn_mfma_f32_16x16x32_f16(A, B1, acc1, 0, 0, 0);
        acc2 = __builtin_amdgcn_mfma_f32_16x16x32_f16(A, B2, acc2, 0, 0, 0);
        acc3 = __builtin_amdgcn_mfma_f32_16x16x32_f16(A, B3, acc3, 0, 0, 0);
        __asm__ volatile("s_waitcnt lgkmcnt(0)" ::: "memory");  // Hs/wAT reads done before next tile's writes
    }

    dh0 = red64(dh0); dh1 = red64(dh1); dh2 = red64(dh2); dh3 = red64(dh3);
    float rd[4];
    rd[0] = 1.f / (dh0 + 1e-16f);
    rd[1] = 1.f / (dh1 + 1e-16f);
    rd[2] = 1.f / (dh2 + 1e-16f);
    rd[3] = 1.f / (dh3 + 1e-16f);
    // combine hi (rows 0-3, lanes 0-15) + lo (rows 4-7, lanes 16-31)
    float tot[4][4];   // [ct][r]
#pragma unroll
    for (int r = 0; r < 4; ++r) {
        tot[0][r] = acc0[r] + __shfl_xor(acc0[r], 16);
        tot[1][r] = acc1[r] + __shfl_xor(acc1[r], 16);
        tot[2][r] = acc2[r] + __shfl_xor(acc2[r], 16);
        tot[3][r] = acc3[r] + __shfl_xor(acc3[r], 16);
    }
    if (lane < 16) {
        size_t ob = (size_t)node * 256 + lane;
#pragma unroll
        for (int r = 0; r < 4; ++r) {
#pragma unroll
            for (int ct = 0; ct < 4; ++ct)
                aggout[ob + r * 64 + ct * 16] = (_Float16)(tot[ct][r] * rd[r]);
        }
    }
}

// ---- MLP on matrix cores: Z = relu(AGG @ C) then 64->3 + log_softmax ------

__global__ __launch_bounds__(256) void mlp_mfma(
        const _Float16* __restrict__ agg,
        const _Float16* __restrict__ CP,
        const float* __restrict__ bcomb,
        const float* __restrict__ wc2, const float* __restrict__ bc2,
        int n, float* __restrict__ out) {
    __shared__ float part[4][16][3];
    int tid = threadIdx.x;
    int lane = tid & 63;
    int w = __builtin_amdgcn_readfirstlane(tid >> 6);   // ct slice
    int c16 = lane & 15, hi = lane >> 4;

    f16x8 bh[8], blo[8];
#pragma unroll
    for (int kt = 0; kt < 8; ++kt) {
        bh[kt]  = *(const f16x8*)(CP + (size_t)(w * 8 + kt) * 512 + lane * 8);
        blo[kt] = *(const f16x8*)(CP + (size_t)(32 + w * 8 + kt) * 512 + lane * 8);
    }
    int col = w * 16 + c16;
    float bc  = bcomb[col];
    float w20 = wc2[col * 3 + 0], w21 = wc2[col * 3 + 1], w22 = wc2[col * 3 + 2];
    float bb0 = bc2[0], bb1 = bc2[1], bb2 = bc2[2];

    int ntiles = (n + 15) >> 4;
    for (int tile = blockIdx.x; tile < ntiles; tile += gridDim.x) {
        int rowb = tile * 16;
        int row = min(rowb + c16, n - 1);
        const _Float16* ap = agg + (size_t)row * 256 + hi * 8;
        f16x8 a[8];
#pragma unroll
        for (int kt = 0; kt < 8; ++kt) a[kt] = *(const f16x8*)(ap + kt * 32);
        f32x4 acc = {0.f, 0.f, 0.f, 0.f};
#pragma unroll
        for (int kt = 0; kt < 8; ++kt) {
            acc = __builtin_amdgcn_mfma_f32_16x16x32_f16(a[kt], bh[kt],  acc, 0, 0, 0);
            acc = __builtin_amdgcn_mfma_f32_16x16x32_f16(a[kt], blo[kt], acc, 0, 0, 0);
        }
        float pr[4][3];
#pragma unroll
        for (int r = 0; r < 4; ++r) {
            float z = fmaxf(acc[r] + bc, 0.f);
            pr[r][0] = red16(z * w20);
            pr[r][1] = red16(z * w21);
            pr[r][2] = red16(z * w22);
        }
        if (c16 == 0) {
#pragma unroll
            for (int r = 0; r < 4; ++r) {
                part[w][hi * 4 + r][0] = pr[r][0];
                part[w][hi * 4 + r][1] = pr[r][1];
                part[w][hi * 4 + r][2] = pr[r][2];
            }
        }
        __syncthreads();
        if (tid < 16) {
            int node = rowb + tid;
            if (node < n) {
                float e0 = part[0][tid][0] + part[1][tid][0] + part[2][tid][0] + part[3][tid][0] + bb0;
                float e1 = part[0][tid][1] + part[1][tid][1] + part[2][tid][1] + part[3][tid][1] + bb1;
                float e2 = part[0][tid][2] + part[1][tid][2] + part[2][tid][2] + part[3][tid][2] + bb2;
                float mx = fmaxf(e0, fmaxf(e1, e2));
                float lse = mx + logf(expf(e0 - mx) + expf(e1 - mx) + expf(e2 - mx));
                out[(size_t)node * 3 + 0] = e0 - lse;
                out[(size_t)node * 3 + 1] = e1 - lse;
                out[(size_t)node * 3 + 2] = e2 - lse;
            }
        }
        __syncthreads();
    }
}

// ---------------------------------------------------------------------------

extern "C" void kernel_launch(void* const* d_in, const int* in_sizes, int n_in,
                              void* d_out, int out_size, void* d_ws, size_t ws_size,
                              hipStream_t stream) {
    const float* x       = (const float*)d_in[0];
    const int*   ei      = (const int*)d_in[1];
    const float* w1      = (const float*)d_in[2];
    const float* b1      = (const float*)d_in[3];
    const float* w2      = (const float*)d_in[4];
    const float* b2      = (const float*)d_in[5];
    const float* w3      = (const float*)d_in[6];
    const float* b3      = (const float*)d_in[7];
    const float* wg      = (const float*)d_in[8];
    const float* bg      = (const float*)d_in[9];
    const float* att_s   = (const float*)d_in[10];
    const float* att_d   = (const float*)d_in[11];
    const float* wc1     = (const float*)d_in[12];
    const float* bc1     = (const float*)d_in[13];
    const float* wc2     = (const float*)d_in[14];
    const float* bc2     = (const float*)d_in[15];
    float* out = (float*)d_out;

    const int N = in_sizes[0] / 8;
    const int E = in_sizes[1] / 2;
    const int* srcv = ei;
    const int* dstv = ei + E;

    char* ws = (char*)d_ws;
    size_t off = 0;
    auto alloc = [&](size_t bytes) -> char* {
        char* p = ws + off;
        off += (bytes + 255) & ~(size_t)255;
        return p;
    };
    int*      counts    = (int*)alloc((size_t)N * 4);
    int*      row_ptr   = (int*)alloc((size_t)(N + 1) * 4);
    int*      cursor    = (int*)alloc((size_t)N * 4);
    int*      col_src   = (int*)alloc((size_t)E * 4);
    int*      blockSums = (int*)alloc(4096 * 4);
    int*      blockOffs = (int*)alloc(4096 * 4);
    float*    dinv      = (float*)alloc((size_t)N * 4);
    float*    rdinv     = (float*)alloc((size_t)N * 4);
    _Float16* xs        = (_Float16*)alloc((size_t)N * 8 * 2);
    float*    a_src     = (float*)alloc((size_t)N * 16);
    float*    a_dst     = (float*)alloc((size_t)N * 16);
    float*    wse       = (float*)alloc(256 * 4);
    float*    wde       = (float*)alloc(256 * 4);
    _Float16* CcombP    = (_Float16*)alloc(64 * 1024);           // fp16 hi+lo B-frags
    float*    bcomb     = (float*)alloc(64 * 4);
    _Float16* bufA      = (_Float16*)alloc((size_t)N * 64 * 2);  // hs1, later h3
    _Float16* bufB      = (_Float16*)alloc((size_t)N * 64 * 2);  // hs2
    _Float16* aggbuf    = (_Float16*)alloc((size_t)N * 256 * 2); // 51.2MB fp16
    _Float16* hs1 = bufA;
    _Float16* hs2 = bufB;
    _Float16* h3  = bufA;   // hs1 dead once layer3 runs
    (void)ws_size; (void)n_in; (void)out_size;

    hipMemsetAsync(counts, 0, (size_t)N * 4, stream);

    const int TPB = 256;
    int range = (N + 7) / 8;
    count_kernel<<<1024, TPB, 0, stream>>>(dstv, E, range, counts);

    int NB = (N + 2047) / 2048;
    scan_pass1<<<NB, TPB, 0, stream>>>(counts, N, blockSums);
    scan_pass2<<<1, 64, 0, stream>>>(blockSums, NB, blockOffs);
    scan_pass3<<<NB, TPB, 0, stream>>>(counts, N, blockOffs, x,
                                       row_ptr, cursor, dinv, rdinv, xs);
    scatter_kernel<<<2048, TPB, 0, stream>>>(srcv, dstv, E, range, cursor, col_src);

    ccomb_kernel<<<257, 64, 0, stream>>>(wg, bg, wc1, bc1, att_s, att_d,
                                         CcombP, bcomb, wse, wde);

    int gridN = (N + 3) / 4;
    gcn_layer1<<<gridN, TPB, 0, stream>>>((const half8*)xs, w1, b1, row_ptr, col_src,
                                          dinv, N, hs1);
    const int G64 = 2048;
    gcn_layer64<false><<<G64, TPB, 0, stream>>>(hs1, w2, b2, row_ptr, col_src,
                                                dinv, rdinv, wse, wde, N, hs2,
                                                nullptr, nullptr);
    gcn_layer64<true><<<G64, TPB, 0, stream>>>(hs2, w3, b3, row_ptr, col_src,
                                               dinv, rdinv, wse, wde, N, h3,
                                               (float4*)a_src, (float4*)a_dst);

    gat_agg<<<gridN, TPB, 0, stream>>>(h3, (const float4*)a_src, (const float4*)a_dst,
                                       row_ptr, col_src, N, aggbuf);
    mlp_mfma<<<2048, TPB, 0, stream>>>(aggbuf, CcombP, bcomb, wc2, bc2, N, out);
}

// Round 7
// 522.470 us; speedup vs baseline: 1.2364x; 1.0555x over previous
//
#include <hip/hip_runtime.h>
#include <math.h>

// ---------------------------------------------------------------------------
// SpatialGNN: 3x GCN (residual) + 4-head GAT + MLP + log_softmax
// N=100000, E=1600000, IN=8, HID=64, HEADS=4, OUT=3
//
// R17 changes vs R16 (551.5us):
//  - gcn_layer64 split into two kernels:
//    * gcn_agg: neighbor gather + red8 + dinv scale -> fp16 agg rows
//      (aliased into aggbuf space, dead until gat_agg). No wreg[64], no
//      LDS barrier, ~40 VGPR -> high occupancy on the latency-bound gather.
//    * gcn_mfma<LAST>: Z = agg @ W on v_mfma_f32_16x16x32_f16 (K=64,
//      16-node tiles, W as fp16 hi+lo frags packed by ccomb_kernel in the
//      SAME fragment order mlp_mfma validated). Epilogue: bias+relu+
//      residual (+LAST: a_src/a_dst via red16 partials + LDS cross-wave).
//  - ccomb_kernel grid 257->385: also packs W2P/W3P (16KB each).
//  - gat_agg, mlp_mfma, CSR build: byte-identical to R16.
// ---------------------------------------------------------------------------

typedef _Float16 half8 __attribute__((ext_vector_type(8)));
typedef _Float16 f16x8 __attribute__((ext_vector_type(8)));
typedef float f32x4 __attribute__((ext_vector_type(4)));

__device__ __forceinline__ float leaky02(float v) { return v > 0.f ? v : 0.2f * v; }

// ---- cross-lane reduction helpers (DPP/swizzle; minimize DS-pipe ops) -----

template <int CTRL>
__device__ __forceinline__ float dpp_add(float v) {
    int iv = __builtin_bit_cast(int, v);
    int r = __builtin_amdgcn_update_dpp(iv, iv, CTRL, 0xF, 0xF, false);
    return v + __builtin_bit_cast(float, r);
}
template <int OFF>
__device__ __forceinline__ float swz_add(float v) {
    int r = __builtin_amdgcn_ds_swizzle(__builtin_bit_cast(int, v), OFF);
    return v + __builtin_bit_cast(float, r);
}
template <int CTRL>
__device__ __forceinline__ float dpp_max(float v) {
    int iv = __builtin_bit_cast(int, v);
    int r = __builtin_amdgcn_update_dpp(iv, iv, CTRL, 0xF, 0xF, false);
    return fmaxf(v, __builtin_bit_cast(float, r));
}
template <int OFF>
__device__ __forceinline__ float swz_max(float v) {
    int r = __builtin_amdgcn_ds_swizzle(__builtin_bit_cast(int, v), OFF);
    return fmaxf(v, __builtin_bit_cast(float, r));
}
__device__ __forceinline__ float red8(float v) {
    v = dpp_add<0xB1>(v);     // xor1
    v = dpp_add<0x4E>(v);     // xor2
    v = swz_add<0x101F>(v);   // xor4
    return v;
}
__device__ __forceinline__ float red16(float v) {
    v = dpp_add<0xB1>(v);
    v = dpp_add<0x4E>(v);
    v = swz_add<0x101F>(v);
    v = dpp_add<0x128>(v);    // row_ror:8 -> completes 16-lane sum
    return v;
}
__device__ __forceinline__ float red64(float v) {
    v = dpp_add<0xB1>(v);
    v = dpp_add<0x4E>(v);
    v = swz_add<0x101F>(v);
    v = dpp_add<0x128>(v);    // xor8: row_ror:8
    v = swz_add<0x401F>(v);   // xor16
    v = v + __shfl_xor(v, 32);
    return v;
}
__device__ __forceinline__ float red64max(float v) {
    v = dpp_max<0xB1>(v);
    v = dpp_max<0x4E>(v);
    v = swz_max<0x101F>(v);
    v = dpp_max<0x128>(v);
    v = swz_max<0x401F>(v);
    v = fmaxf(v, __shfl_xor(v, 32));
    return v;
}

// ---- CSR build ------------------------------------------------------------

// XCD-range-filtered count: group blockIdx&7 counts only its dst range.
__global__ void count_kernel(const int* __restrict__ dst, int E, int range,
                             int* __restrict__ counts) {
    int grp = blockIdx.x & 7;
    int nlo = grp * range;
    int nhi = nlo + range;
    int nblk = gridDim.x >> 3;
    int c = blockIdx.x >> 3;
    int stride = nblk * blockDim.x;
    for (int e = c * blockDim.x + threadIdx.x; e < E; e += stride) {
        int d = dst[e];
        if (d >= nlo && d < nhi) atomicAdd(&counts[d], 1);
    }
}

__global__ void scan_pass1(const int* __restrict__ counts, int n, int* __restrict__ blockSums) {
    __shared__ int sh[256];
    int base = blockIdx.x * 2048;
    int tid = threadIdx.x;
    int s = 0;
#pragma unroll
    for (int j = 0; j < 8; ++j) {
        int idx = base + tid * 8 + j;
        if (idx < n) s += counts[idx];
    }
    sh[tid] = s;
    __syncthreads();
    for (int off = 128; off > 0; off >>= 1) {
        if (tid < off) sh[tid] += sh[tid + off];
        __syncthreads();
    }
    if (tid == 0) blockSums[blockIdx.x] = sh[0];
}

__global__ void scan_pass2(const int* __restrict__ blockSums, int nb, int* __restrict__ blockOffs) {
    if (threadIdx.x == 0 && blockIdx.x == 0) {
        int run = 0;
        for (int i = 0; i < nb; ++i) { blockOffs[i] = run; run += blockSums[i]; }
    }
}

__global__ void scan_pass3(const int* __restrict__ counts, int n,
                           const int* __restrict__ blockOffs,
                           const float* __restrict__ x,
                           int* __restrict__ row_ptr, int* __restrict__ cursor,
                           float* __restrict__ dinv, float* __restrict__ rdinv,
                           _Float16* __restrict__ xs) {
    __shared__ int sh[256];
    int base = blockIdx.x * 2048;
    int tid = threadIdx.x;
    int cnt[8];
    int local = 0;
#pragma unroll
    for (int j = 0; j < 8; ++j) {
        int idx = base + tid * 8 + j;
        cnt[j] = (idx < n) ? counts[idx] : 0;
        local += cnt[j];
    }
    sh[tid] = local;
    __syncthreads();
    for (int off = 1; off < 256; off <<= 1) {
        int v = (tid >= off) ? sh[tid - off] : 0;
        __syncthreads();
        sh[tid] += v;
        __syncthreads();
    }
    int run = blockOffs[blockIdx.x] + sh[tid] - local;
#pragma unroll
    for (int j = 0; j < 8; ++j) {
        int idx = base + tid * 8 + j;
        if (idx < n) {
            row_ptr[idx] = run;
            cursor[idx] = run;
            float dv = rsqrtf((float)(cnt[j] + 1));
            dinv[idx] = dv;
            rdinv[idx] = sqrtf((float)(cnt[j] + 1));
#pragma unroll
            for (int t = 0; t < 8; ++t) xs[idx * 8 + t] = (_Float16)(dv * x[idx * 8 + t]);
            run += cnt[j];
            if (idx == n - 1) row_ptr[n] = run;
        }
    }
}

// XCD-range-filtered scatter (R9, kept): col_src/cursor writes stay XCD-local.
__global__ void scatter_kernel(const int* __restrict__ src, const int* __restrict__ dst,
                               int E, int range,
                               int* __restrict__ cursor, int* __restrict__ col_src) {
    int grp = blockIdx.x & 7;
    int nlo = grp * range;
    int nhi = nlo + range;
    int nblk = gridDim.x >> 3;
    int c = blockIdx.x >> 3;
    int stride = nblk * blockDim.x;
    for (int e = c * blockDim.x + threadIdx.x; e < E; e += stride) {
        int d = dst[e];
        if (d >= nlo && d < nhi) {
            int pos = atomicAdd(&cursor[d], 1);
            col_src[pos] = src[e];
        }
    }
}

// ---- weight precompute: Ccomb + W2P/W3P (fp16 split, B-frag order) --------
// B-frag packing (validated by mlp_mfma): for k index i, out-ch j:
//   kt = i>>5, l = (((i>>3)&3)<<4)|(j&15), e = i&7, ct = j>>4.

__global__ void ccomb_kernel(const float* __restrict__ Wg, const float* __restrict__ bg,
                             const float* __restrict__ wc1, const float* __restrict__ bc1,
                             const float* __restrict__ att_src, const float* __restrict__ att_dst,
                             const float* __restrict__ w2, const float* __restrict__ w3,
                             _Float16* __restrict__ CcombP, float* __restrict__ bcomb,
                             float* __restrict__ wse, float* __restrict__ wde,
                             _Float16* __restrict__ W2P, _Float16* __restrict__ W3P) {
    int bid = blockIdx.x;   // 0..384
    int j = threadIdx.x;    // 64 threads
    if (bid < 256) {
        int i = bid;        // k index (agg channel)
        float s = 0.f;
        for (int c = 0; c < 64; ++c)
            s += Wg[(i & 63) * 256 + (i >> 6) * 64 + c] * wc1[((i >> 6) * 64 + c) * 64 + j];
        _Float16 hi = (_Float16)s;
        _Float16 lo = (_Float16)(s - (float)hi);
        int kt = i >> 5, l = (((i >> 3) & 3) << 4) | (j & 15), e = i & 7, ct = j >> 4;
        CcombP[(ct * 8 + kt) * 512 + l * 8 + e] = hi;
        CcombP[(32 + ct * 8 + kt) * 512 + l * 8 + e] = lo;
    } else if (bid == 256) {
        float s = bc1[j];
        for (int i = 0; i < 256; ++i) s += bg[i] * wc1[i * 64 + j];
        bcomb[j] = s;
#pragma unroll
        for (int h = 0; h < 4; ++h) {
            float ss = 0.f, sd = 0.f;
            for (int c = 0; c < 64; ++c) {
                float w = Wg[j * 256 + h * 64 + c];
                ss += w * att_src[h * 64 + c];
                sd += w * att_dst[h * 64 + c];
            }
            wse[j * 4 + h] = ss;
            wde[j * 4 + h] = sd;
        }
    } else {
        // W2P / W3P: K=64, 8 frags (ct*2+kt) hi + 8 lo
        int i = (bid < 321) ? (bid - 257) : (bid - 321);
        const float* W = (bid < 321) ? w2 : w3;
        _Float16* WP = (bid < 321) ? W2P : W3P;
        float s = W[i * 64 + j];
        _Float16 hi = (_Float16)s;
        _Float16 lo = (_Float16)(s - (float)hi);
        int kt = i >> 5, l = (((i >> 3) & 3) << 4) | (j & 15), e = i & 7, ct = j >> 4;
        WP[(ct * 2 + kt) * 512 + l * 8 + e] = hi;
        WP[(8 + ct * 2 + kt) * 512 + l * 8 + e] = lo;
    }
}

// ---- GCN layer 1: one edge per lane (16B half8 row) -----------------------

__global__ void gcn_layer1(const half8* __restrict__ xs8,
                           const float* __restrict__ W1, const float* __restrict__ b1,
                           const int* __restrict__ row_ptr, const int* __restrict__ col_src,
                           const float* __restrict__ dinv, int n,
                           _Float16* __restrict__ hs1) {
    int tid = threadIdx.x, lane = tid & 63, wid = tid >> 6;
    int node = blockIdx.x * 4 + wid;
    if (node >= n) return;
    int beg = row_ptr[node], end = row_ptr[node + 1];
    int deg = end - beg;
    float acc[8] = {0.f, 0.f, 0.f, 0.f, 0.f, 0.f, 0.f, 0.f};
    for (int base = 0; base < deg; base += 64) {
        int cs = col_src[min(beg + base + lane, end - 1)];
        half8 v = xs8[cs];
        if (base + lane < deg) {
#pragma unroll
            for (int c = 0; c < 8; ++c) acc[c] += (float)v[c];
        }
    }
#pragma unroll
    for (int c = 0; c < 8; ++c) acc[c] = red64(acc[c]);
    half8 sv = xs8[node];
    float di = dinv[node];
    float agg[8];
#pragma unroll
    for (int c = 0; c < 8; ++c) agg[c] = (acc[c] + (float)sv[c]) * di;
    float sum = b1[lane];
#pragma unroll
    for (int k = 0; k < 8; ++k) sum = fmaf(agg[k], W1[k * 64 + lane], sum);
    hs1[node * 64 + lane] = (_Float16)(di * fmaxf(sum, 0.f));
}

// ---- GCN aggregation: gather + red8 + dinv -> fp16 agg rows ---------------
// Per node (1 wave): g=lane&7 edge slots, t=lane>>3 channel chunks; no LDS,
// no barrier, no weights -> small VGPR footprint for the latency-bound phase.

__global__ void gcn_agg(const _Float16* __restrict__ hs_in,
                        const int* __restrict__ row_ptr, const int* __restrict__ col_src,
                        const float* __restrict__ dinv, int n,
                        _Float16* __restrict__ aggout) {
    int tid = threadIdx.x, lane = tid & 63, wid = tid >> 6;
    int node = blockIdx.x * 4 + wid;
    if (node >= n) return;
    int t = lane >> 3, g = lane & 7;
    const half8* hs8 = (const half8*)hs_in;
    int beg = row_ptr[node], end = row_ptr[node + 1];
    int deg = end - beg;
    half8 sv = hs8[node * 8 + t];
    float ac[8];
#pragma unroll
    for (int c = 0; c < 8; ++c) ac[c] = (g == 0) ? (float)sv[c] : 0.f;
    for (int base = 0; base < deg; base += 64) {
        int cs = col_src[min(beg + base + lane, end - 1)];
        int lim = min(deg - base, 64);
        auto bodyF = [&](int eo8) {
            int s = __shfl(cs, eo8 + g);
            half8 v = hs8[s * 8 + t];
#pragma unroll
            for (int c = 0; c < 8; ++c) ac[c] += (float)v[c];
        };
        auto bodyG = [&](int eo8) {
            int eo = eo8 + g;
            int s = __shfl(cs, eo);
            half8 v = hs8[s * 8 + t];
            if (eo < lim) {
#pragma unroll
                for (int c = 0; c < 8; ++c) ac[c] += (float)v[c];
            }
        };
        int eo8 = 0;
        for (; eo8 + 16 <= lim; eo8 += 16) { bodyF(eo8); bodyF(eo8 + 8); }
        if (eo8 < lim) {
            bodyG(eo8);
            eo8 += 8;
            if (eo8 < lim) bodyG(eo8);
        }
    }
    float di = dinv[node];
#pragma unroll
    for (int c = 0; c < 8; ++c) ac[c] = red8(ac[c]) * di;
    if (g == 0) {
        half8 hv;
#pragma unroll
        for (int c = 0; c < 8; ++c) hv[c] = (_Float16)ac[c];
        *(half8*)(aggout + (size_t)node * 64 + t * 8) = hv;
    }
}

// ---- GCN transform on matrix cores: Z = relu(agg @ W + b), residual -------
// 16-node tiles, K=64 (2 k-tiles x hi/lo = 4 MFMA). C: row=(lane>>4)*4+r =
// node-in-tile, col=lane&15 (+wave*16) = out-ch. LAST additionally computes
// a_src/a_dst projections via red16 partials + cross-wave LDS combine.

template <bool LAST>
__global__ __launch_bounds__(256) void gcn_mfma(
        const _Float16* __restrict__ agg,
        const _Float16* __restrict__ WP,
        const float* __restrict__ b,
        const _Float16* __restrict__ hs_in,
        const float* __restrict__ dinv, const float* __restrict__ rdinv,
        const float* __restrict__ wse, const float* __restrict__ wde,
        int n, _Float16* __restrict__ hout,
        float4* __restrict__ a_src4, float4* __restrict__ a_dst4) {
    __shared__ float partS[4][16][4];
    __shared__ float partD[4][16][4];
    int tid = threadIdx.x;
    int lane = tid & 63;
    int w = __builtin_amdgcn_readfirstlane(tid >> 6);   // ct slice
    int c16 = lane & 15, hi = lane >> 4;

    f16x8 bh[2], blo[2];
#pragma unroll
    for (int kt = 0; kt < 2; ++kt) {
        bh[kt]  = *(const f16x8*)(WP + (size_t)(w * 2 + kt) * 512 + lane * 8);
        blo[kt] = *(const f16x8*)(WP + (size_t)(8 + w * 2 + kt) * 512 + lane * 8);
    }
    int col = w * 16 + c16;
    float bl = b[col];
    float4 wev, wdv;
    if (LAST) {
        wev = ((const float4*)wse)[col];
        wdv = ((const float4*)wde)[col];
    }

    int ntiles = (n + 15) >> 4;
    for (int tile = blockIdx.x; tile < ntiles; tile += gridDim.x) {
        int rowb = tile * 16;
        int arow = min(rowb + c16, n - 1);
        const _Float16* ap = agg + (size_t)arow * 64 + hi * 8;
        f16x8 a0 = *(const f16x8*)(ap);
        f16x8 a1 = *(const f16x8*)(ap + 32);
        f32x4 acc = {0.f, 0.f, 0.f, 0.f};
        acc = __builtin_amdgcn_mfma_f32_16x16x32_f16(a0, bh[0],  acc, 0, 0, 0);
        acc = __builtin_amdgcn_mfma_f32_16x16x32_f16(a0, blo[0], acc, 0, 0, 0);
        acc = __builtin_amdgcn_mfma_f32_16x16x32_f16(a1, bh[1],  acc, 0, 0, 0);
        acc = __builtin_amdgcn_mfma_f32_16x16x32_f16(a1, blo[1], acc, 0, 0, 0);
#pragma unroll
        for (int r = 0; r < 4; ++r) {
            int noder = rowb + hi * 4 + r;
            bool ok = noder < n;
            int ni = min(noder, n - 1);
            float hp = rdinv[ni] * (float)hs_in[(size_t)ni * 64 + col];
            float z = fmaxf(acc[r] + bl, 0.f);
            float hv = hp + z;
            if (!LAST) {
                if (ok) hout[(size_t)ni * 64 + col] = (_Float16)(dinv[ni] * hv);
            } else {
                if (ok) hout[(size_t)ni * 64 + col] = (_Float16)hv;
                float s0 = red16(hv * wev.x), s1 = red16(hv * wev.y);
                float s2 = red16(hv * wev.z), s3 = red16(hv * wev.w);
                float d0 = red16(hv * wdv.x), d1 = red16(hv * wdv.y);
                float d2 = red16(hv * wdv.z), d3 = red16(hv * wdv.w);
                if (c16 == 0) {
                    *(float4*)&partS[w][hi * 4 + r][0] = make_float4(s0, s1, s2, s3);
                    *(float4*)&partD[w][hi * 4 + r][0] = make_float4(d0, d1, d2, d3);
                }
            }
        }
        if (LAST) {
            __syncthreads();
            if (tid < 16) {
                int node = rowb + tid;
                if (node < n) {
                    float4 s = make_float4(
                        partS[0][tid][0] + partS[1][tid][0] + partS[2][tid][0] + partS[3][tid][0],
                        partS[0][tid][1] + partS[1][tid][1] + partS[2][tid][1] + partS[3][tid][1],
                        partS[0][tid][2] + partS[1][tid][2] + partS[2][tid][2] + partS[3][tid][2],
                        partS[0][tid][3] + partS[1][tid][3] + partS[2][tid][3] + partS[3][tid][3]);
                    float4 d = make_float4(
                        partD[0][tid][0] + partD[1][tid][0] + partD[2][tid][0] + partD[3][tid][0],
                        partD[0][tid][1] + partD[1][tid][1] + partD[2][tid][1] + partD[3][tid][1],
                        partD[0][tid][2] + partD[1][tid][2] + partD[2][tid][2] + partD[3][tid][2],
                        partD[0][tid][3] + partD[1][tid][3] + partD[2][tid][3] + partD[3][tid][3]);
                    a_src4[node] = s;
                    a_dst4[node] = d;
                }
            }
            __syncthreads();
        }
    }
}

// ---- GAT aggregate on matrix cores (R16, unchanged) -----------------------

__global__ __launch_bounds__(256, 4) void gat_agg(
        const _Float16* __restrict__ h3,
        const float4* __restrict__ a_src4, const float4* __restrict__ a_dst4,
        const int* __restrict__ row_ptr, const int* __restrict__ col_src,
        int n, _Float16* __restrict__ aggout) {
    __shared__ _Float16 HsAll[4][32 * 72];   // 4608B per wave, XOR-swizzled
    __shared__ _Float16 wATAll[4][16 * 40];  // 1280B per wave (rows 8..15 unused)
    int tid = threadIdx.x, lane = tid & 63, wid = tid >> 6;
    int node = blockIdx.x * 4 + wid;
    if (node >= n) return;
    _Float16* Hs = HsAll[wid];
    _Float16* wAT = wATAll[wid];

    int q = lane >> 4, m16 = lane & 15;
    float4 ad = a_dst4[node];
    int beg = row_ptr[node], end = row_ptr[node + 1];
    int deg = end - beg;
    int nslots = deg + 1;

    int swz = q << 4;
    const _Float16* Bb0 = Hs + (size_t)q * 8 * 72 + ((0 * 16 + m16) ^ swz);
    const _Float16* Bb1 = Hs + (size_t)q * 8 * 72 + ((1 * 16 + m16) ^ swz);
    const _Float16* Bb2 = Hs + (size_t)q * 8 * 72 + ((2 * 16 + m16) ^ swz);
    const _Float16* Bb3 = Hs + (size_t)q * 8 * 72 + ((3 * 16 + m16) ^ swz);
    const f16x8* Ab = (const f16x8*)(wAT + m16 * 40 + q * 8);
    int c0 = (lane & 7) * 8;

    f32x4 acc0 = {0.f,0.f,0.f,0.f}, acc1 = {0.f,0.f,0.f,0.f};
    f32x4 acc2 = {0.f,0.f,0.f,0.f}, acc3 = {0.f,0.f,0.f,0.f};
    float dh0 = 0.f, dh1 = 0.f, dh2 = 0.f, dh3 = 0.f;
    float m0 = 0.f, m1 = 0.f, m2 = 0.f, m3 = 0.f;

    for (int base = 0; base < nslots; base += 32) {
        int sl = base + (lane & 31);
        int eidx = max(min(beg + sl - 1, end - 1), 0);
        int cs = (sl == 0) ? node : col_src[eidx];
        float4 as = a_src4[cs];
        float vm = (sl < nslots && lane < 32) ? 1.f : 0.f;
        float l0 = leaky02(as.x + ad.x);
        float l1 = leaky02(as.y + ad.y);
        float l2 = leaky02(as.z + ad.z);
        float l3 = leaky02(as.w + ad.w);
        if (base == 0) {
            m0 = red64max(vm > 0.f ? l0 : -1e30f);
            m1 = red64max(vm > 0.f ? l1 : -1e30f);
            m2 = red64max(vm > 0.f ? l2 : -1e30f);
            m3 = red64max(vm > 0.f ? l3 : -1e30f);
        }
        float w0 = vm * __expf(fminf(l0 - m0, 10.f));
        float w1 = vm * __expf(fminf(l1 - m1, 10.f));
        float w2 = vm * __expf(fminf(l2 - m2, 10.f));
        float w3 = vm * __expf(fminf(l3 - m3, 10.f));
        dh0 += w0; dh1 += w1; dh2 += w2; dh3 += w3;
        if (lane < 32) {
            int s32 = lane & 31;
            _Float16 h0 = (_Float16)w0, h1 = (_Float16)w1;
            _Float16 h2 = (_Float16)w2, h3v = (_Float16)w3;
            wAT[0 * 40 + s32] = h0;
            wAT[1 * 40 + s32] = h1;
            wAT[2 * 40 + s32] = h2;
            wAT[3 * 40 + s32] = h3v;
            wAT[4 * 40 + s32] = (_Float16)(w0 - (float)h0);
            wAT[5 * 40 + s32] = (_Float16)(w1 - (float)h1);
            wAT[6 * 40 + s32] = (_Float16)(w2 - (float)h2);
            wAT[7 * 40 + s32] = (_Float16)(w3 - (float)h3v);
        }
#pragma unroll
        for (int i = 0; i < 4; ++i) {
            int r = i * 8 + (lane >> 3);
            int s = __shfl(cs, r);
            half8 hv = *(const half8*)(h3 + (size_t)s * 64 + c0);
            *(half8*)(Hs + r * 72 + (c0 ^ (i << 4))) = hv;
        }
        __asm__ volatile("s_waitcnt lgkmcnt(0)" ::: "memory");
        f16x8 A = *Ab;
        f16x8 B0, B1, B2, B3;
#pragma unroll
        for (int e = 0; e < 8; ++e) {
            B0[e] = Bb0[e * 72];
            B1[e] = Bb1[e * 72];
            B2[e] = Bb2[e * 72];
            B3[e] = Bb3[e * 72];
        }
        acc0 = __builtin_amdgcn_mfma_f32_16x16x32_f16(A, B0, acc0, 0, 0, 0);
        acc1 = __builtin_amdgcn_mfma_f32_16x16x32_f16(A, B1, acc1, 0, 0, 0);
        acc2 = __builtin_amdgcn_mfma_f32_16x16x32_f16(A, B2, acc2, 0, 0, 0);
        acc3 = __builtin_amdgcn_mfma_f32_16x16x32_f16(A, B3, acc3, 0, 0, 0);
        __asm__ volatile("s_waitcnt lgkmcnt(0)" ::: "memory");
    }

    dh0 = red64(dh0); dh1 = red64(dh1); dh2 = red64(dh2); dh3 = red64(dh3);
    float rd[4];
    rd[0] = 1.f / (dh0 + 1e-16f);
    rd[1] = 1.f / (dh1 + 1e-16f);
    rd[2] = 1.f / (dh2 + 1e-16f);
    rd[3] = 1.f / (dh3 + 1e-16f);
    float tot[4][4];
#pragma unroll
    for (int r = 0; r < 4; ++r) {
        tot[0][r] = acc0[r] + __shfl_xor(acc0[r], 16);
        tot[1][r] = acc1[r] + __shfl_xor(acc1[r], 16);
        tot[2][r] = acc2[r] + __shfl_xor(acc2[r], 16);
        tot[3][r] = acc3[r] + __shfl_xor(acc3[r], 16);
    }
    if (lane < 16) {
        size_t ob = (size_t)node * 256 + lane;
#pragma unroll
        for (int r = 0; r < 4; ++r) {
#pragma unroll
            for (int ct = 0; ct < 4; ++ct)
                aggout[ob + r * 64 + ct * 16] = (_Float16)(tot[ct][r] * rd[r]);
        }
    }
}

// ---- MLP on matrix cores (R16, unchanged) ---------------------------------

__global__ __launch_bounds__(256) void mlp_mfma(
        const _Float16* __restrict__ agg,
        const _Float16* __restrict__ CP,
        const float* __restrict__ bcomb,
        const float* __restrict__ wc2, const float* __restrict__ bc2,
        int n, float* __restrict__ out) {
    __shared__ float part[4][16][3];
    int tid = threadIdx.x;
    int lane = tid & 63;
    int w = __builtin_amdgcn_readfirstlane(tid >> 6);   // ct slice
    int c16 = lane & 15, hi = lane >> 4;

    f16x8 bh[8], blo[8];
#pragma unroll
    for (int kt = 0; kt < 8; ++kt) {
        bh[kt]  = *(const f16x8*)(CP + (size_t)(w * 8 + kt) * 512 + lane * 8);
        blo[kt] = *(const f16x8*)(CP + (size_t)(32 + w * 8 + kt) * 512 + lane * 8);
    }
    int col = w * 16 + c16;
    float bc  = bcomb[col];
    float w20 = wc2[col * 3 + 0], w21 = wc2[col * 3 + 1], w22 = wc2[col * 3 + 2];
    float bb0 = bc2[0], bb1 = bc2[1], bb2 = bc2[2];

    int ntiles = (n + 15) >> 4;
    for (int tile = blockIdx.x; tile < ntiles; tile += gridDim.x) {
        int rowb = tile * 16;
        int row = min(rowb + c16, n - 1);
        const _Float16* ap = agg + (size_t)row * 256 + hi * 8;
        f16x8 a[8];
#pragma unroll
        for (int kt = 0; kt < 8; ++kt) a[kt] = *(const f16x8*)(ap + kt * 32);
        f32x4 acc = {0.f, 0.f, 0.f, 0.f};
#pragma unroll
        for (int kt = 0; kt < 8; ++kt) {
            acc = __builtin_amdgcn_mfma_f32_16x16x32_f16(a[kt], bh[kt],  acc, 0, 0, 0);
            acc = __builtin_amdgcn_mfma_f32_16x16x32_f16(a[kt], blo[kt], acc, 0, 0, 0);
        }
        float pr[4][3];
#pragma unroll
        for (int r = 0; r < 4; ++r) {
            float z = fmaxf(acc[r] + bc, 0.f);
            pr[r][0] = red16(z * w20);
            pr[r][1] = red16(z * w21);
            pr[r][2] = red16(z * w22);
        }
        if (c16 == 0) {
#pragma unroll
            for (int r = 0; r < 4; ++r) {
                part[w][hi * 4 + r][0] = pr[r][0];
                part[w][hi * 4 + r][1] = pr[r][1];
                part[w][hi * 4 + r][2] = pr[r][2];
            }
        }
        __syncthreads();
        if (tid < 16) {
            int node = rowb + tid;
            if (node < n) {
                float e0 = part[0][tid][0] + part[1][tid][0] + part[2][tid][0] + part[3][tid][0] + bb0;
                float e1 = part[0][tid][1] + part[1][tid][1] + part[2][tid][1] + part[3][tid][1] + bb1;
                float e2 = part[0][tid][2] + part[1][tid][2] + part[2][tid][2] + part[3][tid][2] + bb2;
                float mx = fmaxf(e0, fmaxf(e1, e2));
                float lse = mx + logf(expf(e0 - mx) + expf(e1 - mx) + expf(e2 - mx));
                out[(size_t)node * 3 + 0] = e0 - lse;
                out[(size_t)node * 3 + 1] = e1 - lse;
                out[(size_t)node * 3 + 2] = e2 - lse;
            }
        }
        __syncthreads();
    }
}

// ---------------------------------------------------------------------------

extern "C" void kernel_launch(void* const* d_in, const int* in_sizes, int n_in,
                              void* d_out, int out_size, void* d_ws, size_t ws_size,
                              hipStream_t stream) {
    const float* x       = (const float*)d_in[0];
    const int*   ei      = (const int*)d_in[1];
    const float* w1      = (const float*)d_in[2];
    const float* b1      = (const float*)d_in[3];
    const float* w2      = (const float*)d_in[4];
    const float* b2      = (const float*)d_in[5];
    const float* w3      = (const float*)d_in[6];
    const float* b3      = (const float*)d_in[7];
    const float* wg      = (const float*)d_in[8];
    const float* bg      = (const float*)d_in[9];
    const float* att_s   = (const float*)d_in[10];
    const float* att_d   = (const float*)d_in[11];
    const float* wc1     = (const float*)d_in[12];
    const float* bc1     = (const float*)d_in[13];
    const float* wc2     = (const float*)d_in[14];
    const float* bc2     = (const float*)d_in[15];
    float* out = (float*)d_out;

    const int N = in_sizes[0] / 8;
    const int E = in_sizes[1] / 2;
    const int* srcv = ei;
    const int* dstv = ei + E;

    char* ws = (char*)d_ws;
    size_t off = 0;
    auto alloc = [&](size_t bytes) -> char* {
        char* p = ws + off;
        off += (bytes + 255) & ~(size_t)255;
        return p;
    };
    int*      counts    = (int*)alloc((size_t)N * 4);
    int*      row_ptr   = (int*)alloc((size_t)(N + 1) * 4);
    int*      cursor    = (int*)alloc((size_t)N * 4);
    int*      col_src   = (int*)alloc((size_t)E * 4);
    int*      blockSums = (int*)alloc(4096 * 4);
    int*      blockOffs = (int*)alloc(4096 * 4);
    float*    dinv      = (float*)alloc((size_t)N * 4);
    float*    rdinv     = (float*)alloc((size_t)N * 4);
    _Float16* xs        = (_Float16*)alloc((size_t)N * 8 * 2);
    float*    a_src     = (float*)alloc((size_t)N * 16);
    float*    a_dst     = (float*)alloc((size_t)N * 16);
    float*    wse       = (float*)alloc(256 * 4);
    float*    wde       = (float*)alloc(256 * 4);
    _Float16* CcombP    = (_Float16*)alloc(64 * 1024);           // fp16 hi+lo B-frags
    float*    bcomb     = (float*)alloc(64 * 4);
    _Float16* W2P       = (_Float16*)alloc(16 * 1024);           // gcn W frags
    _Float16* W3P       = (_Float16*)alloc(16 * 1024);
    _Float16* bufA      = (_Float16*)alloc((size_t)N * 64 * 2);  // hs1, later h3
    _Float16* bufB      = (_Float16*)alloc((size_t)N * 64 * 2);  // hs2
    _Float16* aggbuf    = (_Float16*)alloc((size_t)N * 256 * 2); // 51.2MB fp16
    _Float16* hs1 = bufA;
    _Float16* hs2 = bufB;
    _Float16* h3  = bufA;   // hs1 dead once layer3 runs
    _Float16* aggA = aggbuf; // gcn agg rows alias aggbuf (dead until gat_agg)
    (void)ws_size; (void)n_in; (void)out_size;

    hipMemsetAsync(counts, 0, (size_t)N * 4, stream);

    const int TPB = 256;
    int range = (N + 7) / 8;
    count_kernel<<<1024, TPB, 0, stream>>>(dstv, E, range, counts);

    int NB = (N + 2047) / 2048;
    scan_pass1<<<NB, TPB, 0, stream>>>(counts, N, blockSums);
    scan_pass2<<<1, 64, 0, stream>>>(blockSums, NB, blockOffs);
    scan_pass3<<<NB, TPB, 0, stream>>>(counts, N, blockOffs, x,
                                       row_ptr, cursor, dinv, rdinv, xs);
    scatter_kernel<<<2048, TPB, 0, stream>>>(srcv, dstv, E, range, cursor, col_src);

    ccomb_kernel<<<385, 64, 0, stream>>>(wg, bg, wc1, bc1, att_s, att_d, w2, w3,
                                         CcombP, bcomb, wse, wde, W2P, W3P);

    int gridN = (N + 3) / 4;
    gcn_layer1<<<gridN, TPB, 0, stream>>>((const half8*)xs, w1, b1, row_ptr, col_src,
                                          dinv, N, hs1);

    gcn_agg<<<gridN, TPB, 0, stream>>>(hs1, row_ptr, col_src, dinv, N, aggA);
    gcn_mfma<false><<<2048, TPB, 0, stream>>>(aggA, W2P, b2, hs1, dinv, rdinv,
                                              nullptr, nullptr, N, hs2,
                                              nullptr, nullptr);
    gcn_agg<<<gridN, TPB, 0, stream>>>(hs2, row_ptr, col_src, dinv, N, aggA);
    gcn_mfma<true><<<2048, TPB, 0, stream>>>(aggA, W3P, b3, hs2, dinv, rdinv,
                                             wse, wde, N, h3,
                                             (float4*)a_src, (float4*)a_dst);

    gat_agg<<<gridN, TPB, 0, stream>>>(h3, (const float4*)a_src, (const float4*)a_dst,
                                       row_ptr, col_src, N, aggbuf);
    mlp_mfma<<<2048, TPB, 0, stream>>>(aggbuf, CcombP, bcomb, wc2, bc2, N, out);
}

// Round 8
// 513.852 us; speedup vs baseline: 1.2571x; 1.0168x over previous
//
#include <hip/hip_runtime.h>
#include <math.h>

// ---------------------------------------------------------------------------
// SpatialGNN: 3x GCN (residual) + 4-head GAT + MLP + log_softmax
// N=100000, E=1600000, IN=8, HID=64, HEADS=4, OUT=3
//
// R18 changes vs R17 (522.5us):
//  - gat_agg small-node fast path: ~47% of nodes have nslots<=16 (Poisson
//    deg 16); they now use ONE K=16 tile via v_mfma_f32_16x16x16_f16:
//    * 16 scalar B-reads (was 32), 2 H-gather iterations (was 4),
//      A-frag = single ds_read_b64, staging by lanes<16 only.
//    * same position-labeling bijection guarantees correctness (A and B
//      staged+read with identical per-lane k labels); no tr-reads.
//  - dh denominator reduction red64 -> red32 (lanes 32-63 contribute
//    exactly 0; readers are lanes<16).
//  - long path (nslots>16), all other kernels: identical to R17.
// ---------------------------------------------------------------------------

typedef _Float16 half8 __attribute__((ext_vector_type(8)));
typedef _Float16 f16x8 __attribute__((ext_vector_type(8)));
typedef _Float16 f16x4 __attribute__((ext_vector_type(4)));
typedef float f32x4 __attribute__((ext_vector_type(4)));

__device__ __forceinline__ float leaky02(float v) { return v > 0.f ? v : 0.2f * v; }

// ---- cross-lane reduction helpers (DPP/swizzle; minimize DS-pipe ops) -----

template <int CTRL>
__device__ __forceinline__ float dpp_add(float v) {
    int iv = __builtin_bit_cast(int, v);
    int r = __builtin_amdgcn_update_dpp(iv, iv, CTRL, 0xF, 0xF, false);
    return v + __builtin_bit_cast(float, r);
}
template <int OFF>
__device__ __forceinline__ float swz_add(float v) {
    int r = __builtin_amdgcn_ds_swizzle(__builtin_bit_cast(int, v), OFF);
    return v + __builtin_bit_cast(float, r);
}
template <int CTRL>
__device__ __forceinline__ float dpp_max(float v) {
    int iv = __builtin_bit_cast(int, v);
    int r = __builtin_amdgcn_update_dpp(iv, iv, CTRL, 0xF, 0xF, false);
    return fmaxf(v, __builtin_bit_cast(float, r));
}
template <int OFF>
__device__ __forceinline__ float swz_max(float v) {
    int r = __builtin_amdgcn_ds_swizzle(__builtin_bit_cast(int, v), OFF);
    return fmaxf(v, __builtin_bit_cast(float, r));
}
__device__ __forceinline__ float red8(float v) {
    v = dpp_add<0xB1>(v);     // xor1
    v = dpp_add<0x4E>(v);     // xor2
    v = swz_add<0x101F>(v);   // xor4
    return v;
}
__device__ __forceinline__ float red16(float v) {
    v = dpp_add<0xB1>(v);
    v = dpp_add<0x4E>(v);
    v = swz_add<0x101F>(v);
    v = dpp_add<0x128>(v);    // row_ror:8 -> completes 16-lane sum
    return v;
}
__device__ __forceinline__ float red32(float v) {   // sum within each 32-lane half
    v = dpp_add<0xB1>(v);
    v = dpp_add<0x4E>(v);
    v = swz_add<0x101F>(v);
    v = dpp_add<0x128>(v);
    v = swz_add<0x401F>(v);
    return v;
}
__device__ __forceinline__ float red64(float v) {
    v = dpp_add<0xB1>(v);
    v = dpp_add<0x4E>(v);
    v = swz_add<0x101F>(v);
    v = dpp_add<0x128>(v);    // xor8: row_ror:8
    v = swz_add<0x401F>(v);   // xor16
    v = v + __shfl_xor(v, 32);
    return v;
}
__device__ __forceinline__ float red32max(float v) {   // max within each 32-lane half
    v = dpp_max<0xB1>(v);
    v = dpp_max<0x4E>(v);
    v = swz_max<0x101F>(v);
    v = dpp_max<0x128>(v);
    v = swz_max<0x401F>(v);
    return v;
}
__device__ __forceinline__ float red64max(float v) {
    v = dpp_max<0xB1>(v);
    v = dpp_max<0x4E>(v);
    v = swz_max<0x101F>(v);
    v = dpp_max<0x128>(v);
    v = swz_max<0x401F>(v);
    v = fmaxf(v, __shfl_xor(v, 32));
    return v;
}

// ---- CSR build ------------------------------------------------------------

// XCD-range-filtered count: group blockIdx&7 counts only its dst range.
__global__ void count_kernel(const int* __restrict__ dst, int E, int range,
                             int* __restrict__ counts) {
    int grp = blockIdx.x & 7;
    int nlo = grp * range;
    int nhi = nlo + range;
    int nblk = gridDim.x >> 3;
    int c = blockIdx.x >> 3;
    int stride = nblk * blockDim.x;
    for (int e = c * blockDim.x + threadIdx.x; e < E; e += stride) {
        int d = dst[e];
        if (d >= nlo && d < nhi) atomicAdd(&counts[d], 1);
    }
}

__global__ void scan_pass1(const int* __restrict__ counts, int n, int* __restrict__ blockSums) {
    __shared__ int sh[256];
    int base = blockIdx.x * 2048;
    int tid = threadIdx.x;
    int s = 0;
#pragma unroll
    for (int j = 0; j < 8; ++j) {
        int idx = base + tid * 8 + j;
        if (idx < n) s += counts[idx];
    }
    sh[tid] = s;
    __syncthreads();
    for (int off = 128; off > 0; off >>= 1) {
        if (tid < off) sh[tid] += sh[tid + off];
        __syncthreads();
    }
    if (tid == 0) blockSums[blockIdx.x] = sh[0];
}

__global__ void scan_pass2(const int* __restrict__ blockSums, int nb, int* __restrict__ blockOffs) {
    if (threadIdx.x == 0 && blockIdx.x == 0) {
        int run = 0;
        for (int i = 0; i < nb; ++i) { blockOffs[i] = run; run += blockSums[i]; }
    }
}

__global__ void scan_pass3(const int* __restrict__ counts, int n,
                           const int* __restrict__ blockOffs,
                           const float* __restrict__ x,
                           int* __restrict__ row_ptr, int* __restrict__ cursor,
                           float* __restrict__ dinv, float* __restrict__ rdinv,
                           _Float16* __restrict__ xs) {
    __shared__ int sh[256];
    int base = blockIdx.x * 2048;
    int tid = threadIdx.x;
    int cnt[8];
    int local = 0;
#pragma unroll
    for (int j = 0; j < 8; ++j) {
        int idx = base + tid * 8 + j;
        cnt[j] = (idx < n) ? counts[idx] : 0;
        local += cnt[j];
    }
    sh[tid] = local;
    __syncthreads();
    for (int off = 1; off < 256; off <<= 1) {
        int v = (tid >= off) ? sh[tid - off] : 0;
        __syncthreads();
        sh[tid] += v;
        __syncthreads();
    }
    int run = blockOffs[blockIdx.x] + sh[tid] - local;
#pragma unroll
    for (int j = 0; j < 8; ++j) {
        int idx = base + tid * 8 + j;
        if (idx < n) {
            row_ptr[idx] = run;
            cursor[idx] = run;
            float dv = rsqrtf((float)(cnt[j] + 1));
            dinv[idx] = dv;
            rdinv[idx] = sqrtf((float)(cnt[j] + 1));
#pragma unroll
            for (int t = 0; t < 8; ++t) xs[idx * 8 + t] = (_Float16)(dv * x[idx * 8 + t]);
            run += cnt[j];
            if (idx == n - 1) row_ptr[n] = run;
        }
    }
}

// XCD-range-filtered scatter (R9, kept): col_src/cursor writes stay XCD-local.
__global__ void scatter_kernel(const int* __restrict__ src, const int* __restrict__ dst,
                               int E, int range,
                               int* __restrict__ cursor, int* __restrict__ col_src) {
    int grp = blockIdx.x & 7;
    int nlo = grp * range;
    int nhi = nlo + range;
    int nblk = gridDim.x >> 3;
    int c = blockIdx.x >> 3;
    int stride = nblk * blockDim.x;
    for (int e = c * blockDim.x + threadIdx.x; e < E; e += stride) {
        int d = dst[e];
        if (d >= nlo && d < nhi) {
            int pos = atomicAdd(&cursor[d], 1);
            col_src[pos] = src[e];
        }
    }
}

// ---- weight precompute: Ccomb + W2P/W3P (fp16 split, B-frag order) --------
// B-frag packing (validated by mlp_mfma): for k index i, out-ch j:
//   kt = i>>5, l = (((i>>3)&3)<<4)|(j&15), e = i&7, ct = j>>4.

__global__ void ccomb_kernel(const float* __restrict__ Wg, const float* __restrict__ bg,
                             const float* __restrict__ wc1, const float* __restrict__ bc1,
                             const float* __restrict__ att_src, const float* __restrict__ att_dst,
                             const float* __restrict__ w2, const float* __restrict__ w3,
                             _Float16* __restrict__ CcombP, float* __restrict__ bcomb,
                             float* __restrict__ wse, float* __restrict__ wde,
                             _Float16* __restrict__ W2P, _Float16* __restrict__ W3P) {
    int bid = blockIdx.x;   // 0..384
    int j = threadIdx.x;    // 64 threads
    if (bid < 256) {
        int i = bid;        // k index (agg channel)
        float s = 0.f;
        for (int c = 0; c < 64; ++c)
            s += Wg[(i & 63) * 256 + (i >> 6) * 64 + c] * wc1[((i >> 6) * 64 + c) * 64 + j];
        _Float16 hi = (_Float16)s;
        _Float16 lo = (_Float16)(s - (float)hi);
        int kt = i >> 5, l = (((i >> 3) & 3) << 4) | (j & 15), e = i & 7, ct = j >> 4;
        CcombP[(ct * 8 + kt) * 512 + l * 8 + e] = hi;
        CcombP[(32 + ct * 8 + kt) * 512 + l * 8 + e] = lo;
    } else if (bid == 256) {
        float s = bc1[j];
        for (int i = 0; i < 256; ++i) s += bg[i] * wc1[i * 64 + j];
        bcomb[j] = s;
#pragma unroll
        for (int h = 0; h < 4; ++h) {
            float ss = 0.f, sd = 0.f;
            for (int c = 0; c < 64; ++c) {
                float w = Wg[j * 256 + h * 64 + c];
                ss += w * att_src[h * 64 + c];
                sd += w * att_dst[h * 64 + c];
            }
            wse[j * 4 + h] = ss;
            wde[j * 4 + h] = sd;
        }
    } else {
        // W2P / W3P: K=64, 8 frags (ct*2+kt) hi + 8 lo
        int i = (bid < 321) ? (bid - 257) : (bid - 321);
        const float* W = (bid < 321) ? w2 : w3;
        _Float16* WP = (bid < 321) ? W2P : W3P;
        float s = W[i * 64 + j];
        _Float16 hi = (_Float16)s;
        _Float16 lo = (_Float16)(s - (float)hi);
        int kt = i >> 5, l = (((i >> 3) & 3) << 4) | (j & 15), e = i & 7, ct = j >> 4;
        WP[(ct * 2 + kt) * 512 + l * 8 + e] = hi;
        WP[(8 + ct * 2 + kt) * 512 + l * 8 + e] = lo;
    }
}

// ---- GCN layer 1: one edge per lane (16B half8 row) -----------------------

__global__ void gcn_layer1(const half8* __restrict__ xs8,
                           const float* __restrict__ W1, const float* __restrict__ b1,
                           const int* __restrict__ row_ptr, const int* __restrict__ col_src,
                           const float* __restrict__ dinv, int n,
                           _Float16* __restrict__ hs1) {
    int tid = threadIdx.x, lane = tid & 63, wid = tid >> 6;
    int node = blockIdx.x * 4 + wid;
    if (node >= n) return;
    int beg = row_ptr[node], end = row_ptr[node + 1];
    int deg = end - beg;
    float acc[8] = {0.f, 0.f, 0.f, 0.f, 0.f, 0.f, 0.f, 0.f};
    for (int base = 0; base < deg; base += 64) {
        int cs = col_src[min(beg + base + lane, end - 1)];
        half8 v = xs8[cs];
        if (base + lane < deg) {
#pragma unroll
            for (int c = 0; c < 8; ++c) acc[c] += (float)v[c];
        }
    }
#pragma unroll
    for (int c = 0; c < 8; ++c) acc[c] = red64(acc[c]);
    half8 sv = xs8[node];
    float di = dinv[node];
    float agg[8];
#pragma unroll
    for (int c = 0; c < 8; ++c) agg[c] = (acc[c] + (float)sv[c]) * di;
    float sum = b1[lane];
#pragma unroll
    for (int k = 0; k < 8; ++k) sum = fmaf(agg[k], W1[k * 64 + lane], sum);
    hs1[node * 64 + lane] = (_Float16)(di * fmaxf(sum, 0.f));
}

// ---- GCN aggregation: gather + red8 + dinv -> fp16 agg rows ---------------

__global__ void gcn_agg(const _Float16* __restrict__ hs_in,
                        const int* __restrict__ row_ptr, const int* __restrict__ col_src,
                        const float* __restrict__ dinv, int n,
                        _Float16* __restrict__ aggout) {
    int tid = threadIdx.x, lane = tid & 63, wid = tid >> 6;
    int node = blockIdx.x * 4 + wid;
    if (node >= n) return;
    int t = lane >> 3, g = lane & 7;
    const half8* hs8 = (const half8*)hs_in;
    int beg = row_ptr[node], end = row_ptr[node + 1];
    int deg = end - beg;
    half8 sv = hs8[node * 8 + t];
    float ac[8];
#pragma unroll
    for (int c = 0; c < 8; ++c) ac[c] = (g == 0) ? (float)sv[c] : 0.f;
    for (int base = 0; base < deg; base += 64) {
        int cs = col_src[min(beg + base + lane, end - 1)];
        int lim = min(deg - base, 64);
        auto bodyF = [&](int eo8) {
            int s = __shfl(cs, eo8 + g);
            half8 v = hs8[s * 8 + t];
#pragma unroll
            for (int c = 0; c < 8; ++c) ac[c] += (float)v[c];
        };
        auto bodyG = [&](int eo8) {
            int eo = eo8 + g;
            int s = __shfl(cs, eo);
            half8 v = hs8[s * 8 + t];
            if (eo < lim) {
#pragma unroll
                for (int c = 0; c < 8; ++c) ac[c] += (float)v[c];
            }
        };
        int eo8 = 0;
        for (; eo8 + 16 <= lim; eo8 += 16) { bodyF(eo8); bodyF(eo8 + 8); }
        if (eo8 < lim) {
            bodyG(eo8);
            eo8 += 8;
            if (eo8 < lim) bodyG(eo8);
        }
    }
    float di = dinv[node];
#pragma unroll
    for (int c = 0; c < 8; ++c) ac[c] = red8(ac[c]) * di;
    if (g == 0) {
        half8 hv;
#pragma unroll
        for (int c = 0; c < 8; ++c) hv[c] = (_Float16)ac[c];
        *(half8*)(aggout + (size_t)node * 64 + t * 8) = hv;
    }
}

// ---- GCN transform on matrix cores: Z = relu(agg @ W + b), residual -------

template <bool LAST>
__global__ __launch_bounds__(256) void gcn_mfma(
        const _Float16* __restrict__ agg,
        const _Float16* __restrict__ WP,
        const float* __restrict__ b,
        const _Float16* __restrict__ hs_in,
        const float* __restrict__ dinv, const float* __restrict__ rdinv,
        const float* __restrict__ wse, const float* __restrict__ wde,
        int n, _Float16* __restrict__ hout,
        float4* __restrict__ a_src4, float4* __restrict__ a_dst4) {
    __shared__ float partS[4][16][4];
    __shared__ float partD[4][16][4];
    int tid = threadIdx.x;
    int lane = tid & 63;
    int w = __builtin_amdgcn_readfirstlane(tid >> 6);   // ct slice
    int c16 = lane & 15, hi = lane >> 4;

    f16x8 bh[2], blo[2];
#pragma unroll
    for (int kt = 0; kt < 2; ++kt) {
        bh[kt]  = *(const f16x8*)(WP + (size_t)(w * 2 + kt) * 512 + lane * 8);
        blo[kt] = *(const f16x8*)(WP + (size_t)(8 + w * 2 + kt) * 512 + lane * 8);
    }
    int col = w * 16 + c16;
    float bl = b[col];
    float4 wev, wdv;
    if (LAST) {
        wev = ((const float4*)wse)[col];
        wdv = ((const float4*)wde)[col];
    }

    int ntiles = (n + 15) >> 4;
    for (int tile = blockIdx.x; tile < ntiles; tile += gridDim.x) {
        int rowb = tile * 16;
        int arow = min(rowb + c16, n - 1);
        const _Float16* ap = agg + (size_t)arow * 64 + hi * 8;
        f16x8 a0 = *(const f16x8*)(ap);
        f16x8 a1 = *(const f16x8*)(ap + 32);
        f32x4 acc = {0.f, 0.f, 0.f, 0.f};
        acc = __builtin_amdgcn_mfma_f32_16x16x32_f16(a0, bh[0],  acc, 0, 0, 0);
        acc = __builtin_amdgcn_mfma_f32_16x16x32_f16(a0, blo[0], acc, 0, 0, 0);
        acc = __builtin_amdgcn_mfma_f32_16x16x32_f16(a1, bh[1],  acc, 0, 0, 0);
        acc = __builtin_amdgcn_mfma_f32_16x16x32_f16(a1, blo[1], acc, 0, 0, 0);
#pragma unroll
        for (int r = 0; r < 4; ++r) {
            int noder = rowb + hi * 4 + r;
            bool ok = noder < n;
            int ni = min(noder, n - 1);
            float hp = rdinv[ni] * (float)hs_in[(size_t)ni * 64 + col];
            float z = fmaxf(acc[r] + bl, 0.f);
            float hv = hp + z;
            if (!LAST) {
                if (ok) hout[(size_t)ni * 64 + col] = (_Float16)(dinv[ni] * hv);
            } else {
                if (ok) hout[(size_t)ni * 64 + col] = (_Float16)hv;
                float s0 = red16(hv * wev.x), s1 = red16(hv * wev.y);
                float s2 = red16(hv * wev.z), s3 = red16(hv * wev.w);
                float d0 = red16(hv * wdv.x), d1 = red16(hv * wdv.y);
                float d2 = red16(hv * wdv.z), d3 = red16(hv * wdv.w);
                if (c16 == 0) {
                    *(float4*)&partS[w][hi * 4 + r][0] = make_float4(s0, s1, s2, s3);
                    *(float4*)&partD[w][hi * 4 + r][0] = make_float4(d0, d1, d2, d3);
                }
            }
        }
        if (LAST) {
            __syncthreads();
            if (tid < 16) {
                int node = rowb + tid;
                if (node < n) {
                    float4 s = make_float4(
                        partS[0][tid][0] + partS[1][tid][0] + partS[2][tid][0] + partS[3][tid][0],
                        partS[0][tid][1] + partS[1][tid][1] + partS[2][tid][1] + partS[3][tid][1],
                        partS[0][tid][2] + partS[1][tid][2] + partS[2][tid][2] + partS[3][tid][2],
                        partS[0][tid][3] + partS[1][tid][3] + partS[2][tid][3] + partS[3][tid][3]);
                    float4 d = make_float4(
                        partD[0][tid][0] + partD[1][tid][0] + partD[2][tid][0] + partD[3][tid][0],
                        partD[0][tid][1] + partD[1][tid][1] + partD[2][tid][1] + partD[3][tid][1],
                        partD[0][tid][2] + partD[1][tid][2] + partD[2][tid][2] + partD[3][tid][2],
                        partD[0][tid][3] + partD[1][tid][3] + partD[2][tid][3] + partD[3][tid][3]);
                    a_src4[node] = s;
                    a_dst4[node] = d;
                }
            }
            __syncthreads();
        }
    }
}

// ---- GAT aggregate on matrix cores (short K=16 path + long K=32 path) -----
//
// Per node (1 wave): out[4h][64c] = W[4,K] x H[K,64], slot 0 = self.
// wAT [m][slot] m-major (stride 40 halfs): m 0-3 = hi heads, 4-7 = lo.
// Hs [slot][72] halves, XOR-swizzled: elem (r,c) at r*72 + (c^((r>>3)<<4)).
// Short path (nslots<=16): one 16x16x16 tile; A = ds_read_b64 of 4
// consecutive slots; 16 scalar B reads; 2 gather iterations.
// Long path (nslots>16): R17's 16x16x32 loop, unchanged.
// C rows 0-3 = hi, 4-7 = lo -> combined with shfl_xor(16).

__global__ __launch_bounds__(256, 4) void gat_agg(
        const _Float16* __restrict__ h3,
        const float4* __restrict__ a_src4, const float4* __restrict__ a_dst4,
        const int* __restrict__ row_ptr, const int* __restrict__ col_src,
        int n, _Float16* __restrict__ aggout) {
    __shared__ _Float16 HsAll[4][32 * 72];   // 4608B per wave, XOR-swizzled
    __shared__ _Float16 wATAll[4][16 * 40];  // 1280B per wave (rows 8..15 unused)
    int tid = threadIdx.x, lane = tid & 63, wid = tid >> 6;
    int node = blockIdx.x * 4 + wid;
    if (node >= n) return;
    _Float16* Hs = HsAll[wid];
    _Float16* wAT = wATAll[wid];

    int q = lane >> 4, m16 = lane & 15;
    float4 ad = a_dst4[node];
    int beg = row_ptr[node], end = row_ptr[node + 1];
    int deg = end - beg;
    int nslots = deg + 1;
    int c0 = (lane & 7) * 8;

    f32x4 acc0 = {0.f,0.f,0.f,0.f}, acc1 = {0.f,0.f,0.f,0.f};
    f32x4 acc2 = {0.f,0.f,0.f,0.f}, acc3 = {0.f,0.f,0.f,0.f};
    float dh0, dh1, dh2, dh3;

    if (nslots <= 16) {
        // ---------------- short path: one K=16 tile ----------------
        int sl = lane & 31;
        int eidx = max(min(beg + sl - 1, end - 1), 0);
        int cs = (sl == 0) ? node : col_src[eidx];
        float4 as = a_src4[cs];
        float vm = (sl < nslots && lane < 32) ? 1.f : 0.f;
        float l0 = leaky02(as.x + ad.x);
        float l1 = leaky02(as.y + ad.y);
        float l2 = leaky02(as.z + ad.z);
        float l3 = leaky02(as.w + ad.w);
        float m0 = red32max(vm > 0.f ? l0 : -1e30f);
        float m1 = red32max(vm > 0.f ? l1 : -1e30f);
        float m2 = red32max(vm > 0.f ? l2 : -1e30f);
        float m3 = red32max(vm > 0.f ? l3 : -1e30f);
        float w0 = vm * __expf(fminf(l0 - m0, 10.f));
        float w1 = vm * __expf(fminf(l1 - m1, 10.f));
        float w2 = vm * __expf(fminf(l2 - m2, 10.f));
        float w3 = vm * __expf(fminf(l3 - m3, 10.f));
        dh0 = w0; dh1 = w1; dh2 = w2; dh3 = w3;
        if (lane < 16) {
            _Float16 h0 = (_Float16)w0, h1 = (_Float16)w1;
            _Float16 h2 = (_Float16)w2, h3v = (_Float16)w3;
            wAT[0 * 40 + sl] = h0;
            wAT[1 * 40 + sl] = h1;
            wAT[2 * 40 + sl] = h2;
            wAT[3 * 40 + sl] = h3v;
            wAT[4 * 40 + sl] = (_Float16)(w0 - (float)h0);
            wAT[5 * 40 + sl] = (_Float16)(w1 - (float)h1);
            wAT[6 * 40 + sl] = (_Float16)(w2 - (float)h2);
            wAT[7 * 40 + sl] = (_Float16)(w3 - (float)h3v);
        }
#pragma unroll
        for (int i = 0; i < 2; ++i) {
            int r = i * 8 + (lane >> 3);         // rows 0..15
            int s = __shfl(cs, r);
            half8 hv = *(const half8*)(h3 + (size_t)s * 64 + c0);
            *(half8*)(Hs + r * 72 + (c0 ^ (i << 4))) = hv;
        }
        __asm__ volatile("s_waitcnt lgkmcnt(0)" ::: "memory");
        // A-frag: row m16, slots q*4..q*4+3 (8B contiguous -> one b64)
        f16x4 A2 = *(const f16x4*)(wAT + m16 * 40 + q * 4);
        // B-frags: rows q*4..q*4+3; swizzle const per lane ((q*4+e)>>3 == q>>1)
        int swz16 = (q >> 1) << 4;
        const _Float16* Cb = Hs + (size_t)(q * 4) * 72;
        f16x4 B0v, B1v, B2v, B3v;
#pragma unroll
        for (int e = 0; e < 4; ++e) {
            int rb = e * 72;
            B0v[e] = Cb[rb + ((0 * 16 + m16) ^ swz16)];
            B1v[e] = Cb[rb + ((1 * 16 + m16) ^ swz16)];
            B2v[e] = Cb[rb + ((2 * 16 + m16) ^ swz16)];
            B3v[e] = Cb[rb + ((3 * 16 + m16) ^ swz16)];
        }
        acc0 = __builtin_amdgcn_mfma_f32_16x16x16f16(A2, B0v, acc0, 0, 0, 0);
        acc1 = __builtin_amdgcn_mfma_f32_16x16x16f16(A2, B1v, acc1, 0, 0, 0);
        acc2 = __builtin_amdgcn_mfma_f32_16x16x16f16(A2, B2v, acc2, 0, 0, 0);
        acc3 = __builtin_amdgcn_mfma_f32_16x16x16f16(A2, B3v, acc3, 0, 0, 0);
    } else {
        // ---------------- long path: K=32 tiles (R17, unchanged) ----------------
        int swz = q << 4;
        const _Float16* Bb0 = Hs + (size_t)q * 8 * 72 + ((0 * 16 + m16) ^ swz);
        const _Float16* Bb1 = Hs + (size_t)q * 8 * 72 + ((1 * 16 + m16) ^ swz);
        const _Float16* Bb2 = Hs + (size_t)q * 8 * 72 + ((2 * 16 + m16) ^ swz);
        const _Float16* Bb3 = Hs + (size_t)q * 8 * 72 + ((3 * 16 + m16) ^ swz);
        const f16x8* Ab = (const f16x8*)(wAT + m16 * 40 + q * 8);
        float dA = 0.f, dB = 0.f, dC = 0.f, dD = 0.f;
        float m0 = 0.f, m1 = 0.f, m2 = 0.f, m3 = 0.f;
        for (int base = 0; base < nslots; base += 32) {
            int sl = base + (lane & 31);
            int eidx = max(min(beg + sl - 1, end - 1), 0);
            int cs = (sl == 0) ? node : col_src[eidx];
            float4 as = a_src4[cs];
            float vm = (sl < nslots && lane < 32) ? 1.f : 0.f;
            float l0 = leaky02(as.x + ad.x);
            float l1 = leaky02(as.y + ad.y);
            float l2 = leaky02(as.z + ad.z);
            float l3 = leaky02(as.w + ad.w);
            if (base == 0) {
                m0 = red64max(vm > 0.f ? l0 : -1e30f);
                m1 = red64max(vm > 0.f ? l1 : -1e30f);
                m2 = red64max(vm > 0.f ? l2 : -1e30f);
                m3 = red64max(vm > 0.f ? l3 : -1e30f);
            }
            float w0 = vm * __expf(fminf(l0 - m0, 10.f));
            float w1 = vm * __expf(fminf(l1 - m1, 10.f));
            float w2 = vm * __expf(fminf(l2 - m2, 10.f));
            float w3 = vm * __expf(fminf(l3 - m3, 10.f));
            dA += w0; dB += w1; dC += w2; dD += w3;
            if (lane < 32) {
                int s32 = lane & 31;
                _Float16 h0 = (_Float16)w0, h1 = (_Float16)w1;
                _Float16 h2 = (_Float16)w2, h3v = (_Float16)w3;
                wAT[0 * 40 + s32] = h0;
                wAT[1 * 40 + s32] = h1;
                wAT[2 * 40 + s32] = h2;
                wAT[3 * 40 + s32] = h3v;
                wAT[4 * 40 + s32] = (_Float16)(w0 - (float)h0);
                wAT[5 * 40 + s32] = (_Float16)(w1 - (float)h1);
                wAT[6 * 40 + s32] = (_Float16)(w2 - (float)h2);
                wAT[7 * 40 + s32] = (_Float16)(w3 - (float)h3v);
            }
#pragma unroll
            for (int i = 0; i < 4; ++i) {
                int r = i * 8 + (lane >> 3);
                int s = __shfl(cs, r);
                half8 hv = *(const half8*)(h3 + (size_t)s * 64 + c0);
                *(half8*)(Hs + r * 72 + (c0 ^ (i << 4))) = hv;
            }
            __asm__ volatile("s_waitcnt lgkmcnt(0)" ::: "memory");
            f16x8 A = *Ab;
            f16x8 B0, B1, B2, B3;
#pragma unroll
            for (int e = 0; e < 8; ++e) {
                B0[e] = Bb0[e * 72];
                B1[e] = Bb1[e * 72];
                B2[e] = Bb2[e * 72];
                B3[e] = Bb3[e * 72];
            }
            acc0 = __builtin_amdgcn_mfma_f32_16x16x32_f16(A, B0, acc0, 0, 0, 0);
            acc1 = __builtin_amdgcn_mfma_f32_16x16x32_f16(A, B1, acc1, 0, 0, 0);
            acc2 = __builtin_amdgcn_mfma_f32_16x16x32_f16(A, B2, acc2, 0, 0, 0);
            acc3 = __builtin_amdgcn_mfma_f32_16x16x32_f16(A, B3, acc3, 0, 0, 0);
            __asm__ volatile("s_waitcnt lgkmcnt(0)" ::: "memory");
        }
        dh0 = dA; dh1 = dB; dh2 = dC; dh3 = dD;
    }

    // denominators: w nonzero only on lanes 0-31; readers are lanes < 16
    dh0 = red32(dh0); dh1 = red32(dh1); dh2 = red32(dh2); dh3 = red32(dh3);
    float rd[4];
    rd[0] = 1.f / (dh0 + 1e-16f);
    rd[1] = 1.f / (dh1 + 1e-16f);
    rd[2] = 1.f / (dh2 + 1e-16f);
    rd[3] = 1.f / (dh3 + 1e-16f);
    // combine hi (rows 0-3, lanes 0-15) + lo (rows 4-7, lanes 16-31)
    float tot[4][4];
#pragma unroll
    for (int r = 0; r < 4; ++r) {
        tot[0][r] = acc0[r] + __shfl_xor(acc0[r], 16);
        tot[1][r] = acc1[r] + __shfl_xor(acc1[r], 16);
        tot[2][r] = acc2[r] + __shfl_xor(acc2[r], 16);
        tot[3][r] = acc3[r] + __shfl_xor(acc3[r], 16);
    }
    if (lane < 16) {
        size_t ob = (size_t)node * 256 + lane;
#pragma unroll
        for (int r = 0; r < 4; ++r) {
#pragma unroll
            for (int ct = 0; ct < 4; ++ct)
                aggout[ob + r * 64 + ct * 16] = (_Float16)(tot[ct][r] * rd[r]);
        }
    }
}

// ---- MLP on matrix cores (unchanged) --------------------------------------

__global__ __launch_bounds__(256) void mlp_mfma(
        const _Float16* __restrict__ agg,
        const _Float16* __restrict__ CP,
        const float* __restrict__ bcomb,
        const float* __restrict__ wc2, const float* __restrict__ bc2,
        int n, float* __restrict__ out) {
    __shared__ float part[4][16][3];
    int tid = threadIdx.x;
    int lane = tid & 63;
    int w = __builtin_amdgcn_readfirstlane(tid >> 6);   // ct slice
    int c16 = lane & 15, hi = lane >> 4;

    f16x8 bh[8], blo[8];
#pragma unroll
    for (int kt = 0; kt < 8; ++kt) {
        bh[kt]  = *(const f16x8*)(CP + (size_t)(w * 8 + kt) * 512 + lane * 8);
        blo[kt] = *(const f16x8*)(CP + (size_t)(32 + w * 8 + kt) * 512 + lane * 8);
    }
    int col = w * 16 + c16;
    float bc  = bcomb[col];
    float w20 = wc2[col * 3 + 0], w21 = wc2[col * 3 + 1], w22 = wc2[col * 3 + 2];
    float bb0 = bc2[0], bb1 = bc2[1], bb2 = bc2[2];

    int ntiles = (n + 15) >> 4;
    for (int tile = blockIdx.x; tile < ntiles; tile += gridDim.x) {
        int rowb = tile * 16;
        int row = min(rowb + c16, n - 1);
        const _Float16* ap = agg + (size_t)row * 256 + hi * 8;
        f16x8 a[8];
#pragma unroll
        for (int kt = 0; kt < 8; ++kt) a[kt] = *(const f16x8*)(ap + kt * 32);
        f32x4 acc = {0.f, 0.f, 0.f, 0.f};
#pragma unroll
        for (int kt = 0; kt < 8; ++kt) {
            acc = __builtin_amdgcn_mfma_f32_16x16x32_f16(a[kt], bh[kt],  acc, 0, 0, 0);
            acc = __builtin_amdgcn_mfma_f32_16x16x32_f16(a[kt], blo[kt], acc, 0, 0, 0);
        }
        float pr[4][3];
#pragma unroll
        for (int r = 0; r < 4; ++r) {
            float z = fmaxf(acc[r] + bc, 0.f);
            pr[r][0] = red16(z * w20);
            pr[r][1] = red16(z * w21);
            pr[r][2] = red16(z * w22);
        }
        if (c16 == 0) {
#pragma unroll
            for (int r = 0; r < 4; ++r) {
                part[w][hi * 4 + r][0] = pr[r][0];
                part[w][hi * 4 + r][1] = pr[r][1];
                part[w][hi * 4 + r][2] = pr[r][2];
            }
        }
        __syncthreads();
        if (tid < 16) {
            int node = rowb + tid;
            if (node < n) {
                float e0 = part[0][tid][0] + part[1][tid][0] + part[2][tid][0] + part[3][tid][0] + bb0;
                float e1 = part[0][tid][1] + part[1][tid][1] + part[2][tid][1] + part[3][tid][1] + bb1;
                float e2 = part[0][tid][2] + part[1][tid][2] + part[2][tid][2] + part[3][tid][2] + bb2;
                float mx = fmaxf(e0, fmaxf(e1, e2));
                float lse = mx + logf(expf(e0 - mx) + expf(e1 - mx) + expf(e2 - mx));
                out[(size_t)node * 3 + 0] = e0 - lse;
                out[(size_t)node * 3 + 1] = e1 - lse;
                out[(size_t)node * 3 + 2] = e2 - lse;
            }
        }
        __syncthreads();
    }
}

// ---------------------------------------------------------------------------

extern "C" void kernel_launch(void* const* d_in, const int* in_sizes, int n_in,
                              void* d_out, int out_size, void* d_ws, size_t ws_size,
                              hipStream_t stream) {
    const float* x       = (const float*)d_in[0];
    const int*   ei      = (const int*)d_in[1];
    const float* w1      = (const float*)d_in[2];
    const float* b1      = (const float*)d_in[3];
    const float* w2      = (const float*)d_in[4];
    const float* b2      = (const float*)d_in[5];
    const float* w3      = (const float*)d_in[6];
    const float* b3      = (const float*)d_in[7];
    const float* wg      = (const float*)d_in[8];
    const float* bg      = (const float*)d_in[9];
    const float* att_s   = (const float*)d_in[10];
    const float* att_d   = (const float*)d_in[11];
    const float* wc1     = (const float*)d_in[12];
    const float* bc1     = (const float*)d_in[13];
    const float* wc2     = (const float*)d_in[14];
    const float* bc2     = (const float*)d_in[15];
    float* out = (float*)d_out;

    const int N = in_sizes[0] / 8;
    const int E = in_sizes[1] / 2;
    const int* srcv = ei;
    const int* dstv = ei + E;

    char* ws = (char*)d_ws;
    size_t off = 0;
    auto alloc = [&](size_t bytes) -> char* {
        char* p = ws + off;
        off += (bytes + 255) & ~(size_t)255;
        return p;
    };
    int*      counts    = (int*)alloc((size_t)N * 4);
    int*      row_ptr   = (int*)alloc((size_t)(N + 1) * 4);
    int*      cursor    = (int*)alloc((size_t)N * 4);
    int*      col_src   = (int*)alloc((size_t)E * 4);
    int*      blockSums = (int*)alloc(4096 * 4);
    int*      blockOffs = (int*)alloc(4096 * 4);
    float*    dinv      = (float*)alloc((size_t)N * 4);
    float*    rdinv     = (float*)alloc((size_t)N * 4);
    _Float16* xs        = (_Float16*)alloc((size_t)N * 8 * 2);
    float*    a_src     = (float*)alloc((size_t)N * 16);
    float*    a_dst     = (float*)alloc((size_t)N * 16);
    float*    wse       = (float*)alloc(256 * 4);
    float*    wde       = (float*)alloc(256 * 4);
    _Float16* CcombP    = (_Float16*)alloc(64 * 1024);           // fp16 hi+lo B-frags
    float*    bcomb     = (float*)alloc(64 * 4);
    _Float16* W2P       = (_Float16*)alloc(16 * 1024);           // gcn W frags
    _Float16* W3P       = (_Float16*)alloc(16 * 1024);
    _Float16* bufA      = (_Float16*)alloc((size_t)N * 64 * 2);  // hs1, later h3
    _Float16* bufB      = (_Float16*)alloc((size_t)N * 64 * 2);  // hs2
    _Float16* aggbuf    = (_Float16*)alloc((size_t)N * 256 * 2); // 51.2MB fp16
    _Float16* hs1 = bufA;
    _Float16* hs2 = bufB;
    _Float16* h3  = bufA;   // hs1 dead once layer3 runs
    _Float16* aggA = aggbuf; // gcn agg rows alias aggbuf (dead until gat_agg)
    (void)ws_size; (void)n_in; (void)out_size;

    hipMemsetAsync(counts, 0, (size_t)N * 4, stream);

    const int TPB = 256;
    int range = (N + 7) / 8;
    count_kernel<<<1024, TPB, 0, stream>>>(dstv, E, range, counts);

    int NB = (N + 2047) / 2048;
    scan_pass1<<<NB, TPB, 0, stream>>>(counts, N, blockSums);
    scan_pass2<<<1, 64, 0, stream>>>(blockSums, NB, blockOffs);
    scan_pass3<<<NB, TPB, 0, stream>>>(counts, N, blockOffs, x,
                                       row_ptr, cursor, dinv, rdinv, xs);
    scatter_kernel<<<2048, TPB, 0, stream>>>(srcv, dstv, E, range, cursor, col_src);

    ccomb_kernel<<<385, 64, 0, stream>>>(wg, bg, wc1, bc1, att_s, att_d, w2, w3,
                                         CcombP, bcomb, wse, wde, W2P, W3P);

    int gridN = (N + 3) / 4;
    gcn_layer1<<<gridN, TPB, 0, stream>>>((const half8*)xs, w1, b1, row_ptr, col_src,
                                          dinv, N, hs1);

    gcn_agg<<<gridN, TPB, 0, stream>>>(hs1, row_ptr, col_src, dinv, N, aggA);
    gcn_mfma<false><<<2048, TPB, 0, stream>>>(aggA, W2P, b2, hs1, dinv, rdinv,
                                              nullptr, nullptr, N, hs2,
                                              nullptr, nullptr);
    gcn_agg<<<gridN, TPB, 0, stream>>>(hs2, row_ptr, col_src, dinv, N, aggA);
    gcn_mfma<true><<<2048, TPB, 0, stream>>>(aggA, W3P, b3, hs2, dinv, rdinv,
                                             wse, wde, N, h3,
                                             (float4*)a_src, (float4*)a_dst);

    gat_agg<<<gridN, TPB, 0, stream>>>(h3, (const float4*)a_src, (const float4*)a_dst,
                                       row_ptr, col_src, N, aggbuf);
    mlp_mfma<<<2048, TPB, 0, stream>>>(aggbuf, CcombP, bcomb, wc2, bc2, N, out);
}